// Round 11
// baseline (395.313 us; speedup 1.0000x reference)
//
#include <hip/hip_runtime.h>
#include <hip/hip_cooperative_groups.h>
#include <math.h>

namespace cg = cooperative_groups;

#define N_NODES 4096
#define DMODEL  512
#define NHEAD   8
#define DHEAD   64
#define DFF     2048
#define NEDGE   65536
#define QKVLD   1536

typedef unsigned short u16;
typedef __bf16 bf16x8 __attribute__((ext_vector_type(8)));
typedef float  f32x4  __attribute__((ext_vector_type(4)));
typedef short  s16x4  __attribute__((ext_vector_type(4)));

#if defined(__has_builtin)
#if __has_builtin(__builtin_amdgcn_mfma_f32_16x16x16bf16_1k)
#define HAS_MFMA_1K 1
#endif
#if __has_builtin(__builtin_amdgcn_global_load_lds)
#define HAS_GLOAD_LDS 1
#endif
#endif

__device__ inline float fast_exp2(float x) {
    return __builtin_amdgcn_exp2f(x);   // v_exp_f32: 2^x native
}

__device__ inline f32x4 mfma16(bf16x8 a, bf16x8 b, f32x4 c) {
    return __builtin_amdgcn_mfma_f32_16x16x32_bf16(a, b, c, 0, 0, 0);
}

__device__ inline u16 f2bf(float f) {  // RNE
    union { float f; unsigned u; } v; v.f = f;
    unsigned r = v.u + 0x7fff + ((v.u >> 16) & 1);
    return (u16)(r >> 16);
}

#ifdef HAS_MFMA_1K
__device__ inline f32x4 mfma1k(s16x4 a, s16x4 b, f32x4 c) {
    return __builtin_amdgcn_mfma_f32_16x16x16bf16_1k(a, b, c, 0, 0, 0);
}
__device__ inline s16x4 pack_bf4(f32x4 p) {
    union { float f; unsigned u; } a0, a1, a2, a3;
    a0.f = p[0]; a1.f = p[1]; a2.f = p[2]; a3.f = p[3];
    unsigned lo = __builtin_amdgcn_perm(a1.u + 0x8000u, a0.u + 0x8000u, 0x07060302u);
    unsigned hi = __builtin_amdgcn_perm(a3.u + 0x8000u, a2.u + 0x8000u, 0x07060302u);
    union { unsigned u[2]; s16x4 v; } r;
    r.u[0] = lo; r.u[1] = hi;
    return r.v;
}
#else
// Host-pass stubs: gfx950 device pass always defines HAS_MFMA_1K. Parsed, never executed.
__device__ inline f32x4 mfma1k(s16x4 a, s16x4 b, f32x4 c) { return c; }
__device__ inline s16x4 pack_bf4(f32x4 p) {
    union { u16 u[4]; s16x4 v; } r;
    r.u[0] = f2bf(p[0]); r.u[1] = f2bf(p[1]); r.u[2] = f2bf(p[2]); r.u[3] = f2bf(p[3]);
    return r.v;
}
#endif

// async global->LDS, 16B/lane. LDS dest is wave-uniform base + lane*16 (linear!).
__device__ inline void gld16(const u16* g, u16* l) {
#ifdef HAS_GLOAD_LDS
    __builtin_amdgcn_global_load_lds((const __attribute__((address_space(1))) void*)g,
                                     (__attribute__((address_space(3))) void*)l,
                                     16, 0, 0);
#else
    // host-parse stub; device pass on gfx950 always takes the builtin path.
    *(uint4*)l = *(const uint4*)g;
#endif
}

__device__ inline float bf2f(u16 v) {
    union { unsigned u; float f; } t; t.u = ((unsigned)v) << 16; return t.f;
}

__device__ inline float gelu_tanh(float x) {
    float x3 = x * x * x;
    float t = tanhf(0.7978845608028654f * (x + 0.044715f * x3));
    return 0.5f * x * (1.0f + t);
}

#define GBN 128
#define GBK 32
#define GP  40

// ---------------------------------------------------------------------------
// MFMA bf16 GEMM 64x128x32, 512 threads = 8 waves, double-buffered via
// global_load_lds (16B/lane, linear LDS [rows][32]). (W2, Wa)
// ---------------------------------------------------------------------------
template <int ACT, int OBF16>
__launch_bounds__(512)
__global__ void mfma_gemm64(const u16* __restrict__ A, const u16* __restrict__ Bt,
                            const float* __restrict__ bias, const float* __restrict__ res,
                            void* __restrict__ Cout, int M, int Nn, int K, float scale,
                            int ldC, int ldRes) {
    __shared__ u16 Asm[2][64 * 32];
    __shared__ u16 Bsm[2][128 * 32];

    const int tid = threadIdx.x;
    const int w = tid >> 6;
    const int lane = tid & 63;
    const int quad = lane >> 4;
    const int l15 = lane & 15;
    const int row0 = blockIdx.y * 64;
    const int col0 = blockIdx.x * GBN;
    const int rh = (w & 1) * 32;
    const int cg = (w >> 1) * 32;

    f32x4 acc[2][2];
#pragma unroll
    for (int i = 0; i < 2; ++i)
#pragma unroll
        for (int j = 0; j < 2; ++j) acc[i][j] = (f32x4){0.f, 0.f, 0.f, 0.f};

    const int crow = lane >> 2;
    const int ck = (lane & 3) * 8;
    const u16* gB = &Bt[(size_t)(col0 + w * 16 + crow) * K + ck];
    const u16* gA = &A [(size_t)(row0 + (w & 3) * 16 + crow) * K + ck];
    const int lBo = w * 512;
    const int lAo = (w & 3) * 512;

    gld16(gB, &Bsm[0][lBo]);
    if (w < 4) gld16(gA, &Asm[0][lAo]);
    __syncthreads();

    const int nT = K / GBK;
    for (int t = 0; t < nT; ++t) {
        const int buf = t & 1;
        if (t + 1 < nT) {
            const int k0 = (t + 1) * GBK;
            gld16(gB + k0, &Bsm[buf ^ 1][lBo]);
            if (w < 4) gld16(gA + k0, &Asm[buf ^ 1][lAo]);
        }
        bf16x8 af[2], bf[2];
#pragma unroll
        for (int i = 0; i < 2; ++i)
            af[i] = *(const bf16x8*)&Asm[buf][(rh + i * 16 + l15) * 32 + quad * 8];
#pragma unroll
        for (int j = 0; j < 2; ++j)
            bf[j] = *(const bf16x8*)&Bsm[buf][(cg + j * 16 + l15) * 32 + quad * 8];
#pragma unroll
        for (int i = 0; i < 2; ++i)
#pragma unroll
            for (int j = 0; j < 2; ++j)
                acc[i][j] = mfma16(af[i], bf[j], acc[i][j]);
        if (t + 1 < nT) __syncthreads();
    }

#pragma unroll
    for (int j = 0; j < 2; ++j) {
        const int col = col0 + cg + j * 16 + l15;
        const float bc = bias ? bias[col] : 0.f;
#pragma unroll
        for (int i = 0; i < 2; ++i) {
#pragma unroll
            for (int r = 0; r < 4; ++r) {
                const int row = row0 + rh + i * 16 + quad * 4 + r;
                float o = (acc[i][j][r] + bc) * scale;
                if (ACT == 1) o = gelu_tanh(o);
                if (res) o += res[(size_t)row * ldRes + col];
                if (OBF16)
                    ((u16*)Cout)[(size_t)row * ldC + col] = f2bf(o);
                else
                    ((float*)Cout)[(size_t)row * ldC + col] = o;
            }
        }
    }
}

// ---------------------------------------------------------------------------
// MFMA bf16 GEMM 128x128x32, 512 threads = 8 waves, acc[2][4] per wave,
// gload_lds staging, double-buffered. (W1)
// ---------------------------------------------------------------------------
template <int ACT, int OBF16>
__launch_bounds__(512)
__global__ void mfma_gemm128(const u16* __restrict__ A, const u16* __restrict__ Bt,
                             const float* __restrict__ bias, const float* __restrict__ res,
                             void* __restrict__ Cout, int M, int Nn, int K, float scale,
                             int ldC, int ldRes) {
    __shared__ u16 Asm[2][128 * 32];
    __shared__ u16 Bsm[2][128 * 32];

    const int tid = threadIdx.x;
    const int w = tid >> 6;
    const int lane = tid & 63;
    const int quad = lane >> 4;
    const int l15 = lane & 15;
    const int row0 = blockIdx.y * 128;
    const int col0 = blockIdx.x * 128;
    const int rh = (w & 3) * 32;
    const int cg = (w >> 2) * 64;

    f32x4 acc[2][4];
#pragma unroll
    for (int i = 0; i < 2; ++i)
#pragma unroll
        for (int j = 0; j < 4; ++j) acc[i][j] = (f32x4){0.f, 0.f, 0.f, 0.f};

    const int crow = lane >> 2;
    const int ck = (lane & 3) * 8;
    const u16* gA = &A [(size_t)(row0 + w * 16 + crow) * K + ck];
    const u16* gB = &Bt[(size_t)(col0 + w * 16 + crow) * K + ck];
    const int lo = w * 512;

    gld16(gA, &Asm[0][lo]);
    gld16(gB, &Bsm[0][lo]);
    __syncthreads();

    const int nT = K / GBK;
    for (int t = 0; t < nT; ++t) {
        const int buf = t & 1;
        if (t + 1 < nT) {
            const int k0 = (t + 1) * GBK;
            gld16(gA + k0, &Asm[buf ^ 1][lo]);
            gld16(gB + k0, &Bsm[buf ^ 1][lo]);
        }
        bf16x8 af[2], bf[4];
#pragma unroll
        for (int i = 0; i < 2; ++i)
            af[i] = *(const bf16x8*)&Asm[buf][(rh + i * 16 + l15) * 32 + quad * 8];
#pragma unroll
        for (int j = 0; j < 4; ++j)
            bf[j] = *(const bf16x8*)&Bsm[buf][(cg + j * 16 + l15) * 32 + quad * 8];
#pragma unroll
        for (int i = 0; i < 2; ++i)
#pragma unroll
            for (int j = 0; j < 4; ++j)
                acc[i][j] = mfma16(af[i], bf[j], acc[i][j]);
        if (t + 1 < nT) __syncthreads();
    }

#pragma unroll
    for (int j = 0; j < 4; ++j) {
        const int col = col0 + cg + j * 16 + l15;
        const float bc = bias ? bias[col] : 0.f;
#pragma unroll
        for (int i = 0; i < 2; ++i) {
#pragma unroll
            for (int r = 0; r < 4; ++r) {
                const int row = row0 + rh + i * 16 + quad * 4 + r;
                float o = (acc[i][j][r] + bc) * scale;
                if (ACT == 1) o = gelu_tanh(o);
                if (res) o += res[(size_t)row * ldRes + col];
                if (OBF16)
                    ((u16*)Cout)[(size_t)row * ldC + col] = f2bf(o);
                else
                    ((float*)Cout)[(size_t)row * ldC + col] = o;
            }
        }
    }
}

// ---------------------------------------------------------------------------
// Fused Wo GEMM with on-the-fly attention split-reduce in the A path.
// NSPLIT=4: slices in Ob0 (sp 0,1) and Ob1 (sp 2,3). 512 thr.
// B via global_load_lds (linear [128][32]); A computed -> reg-staged (GP=40).
// ---------------------------------------------------------------------------
__device__ inline uint4 reduce4_norm(const u16* b0, const u16* b1, size_t off, float linv) {
    const size_t OFF = (size_t)N_NODES * DMODEL;
    float s[8] = {0.f, 0.f, 0.f, 0.f, 0.f, 0.f, 0.f, 0.f};
    const u16* bs[2] = {b0, b1};
#pragma unroll
    for (int b = 0; b < 2; ++b)
#pragma unroll
        for (int k = 0; k < 2; ++k) {
            uint4 v = *(const uint4*)(bs[b] + k * OFF + off);
            unsigned uu[4] = {v.x, v.y, v.z, v.w};
#pragma unroll
            for (int t = 0; t < 4; ++t) {
                s[2 * t]     += bf2f((u16)(uu[t] & 0xffff));
                s[2 * t + 1] += bf2f((u16)(uu[t] >> 16));
            }
        }
    uint4 r;
    r.x = (unsigned)f2bf(s[0] * linv) | ((unsigned)f2bf(s[1] * linv) << 16);
    r.y = (unsigned)f2bf(s[2] * linv) | ((unsigned)f2bf(s[3] * linv) << 16);
    r.z = (unsigned)f2bf(s[4] * linv) | ((unsigned)f2bf(s[5] * linv) << 16);
    r.w = (unsigned)f2bf(s[6] * linv) | ((unsigned)f2bf(s[7] * linv) << 16);
    return r;
}

__launch_bounds__(512)
__global__ void wo_gemm(const u16* __restrict__ Ob0, const u16* __restrict__ Ob1,
                        const float* __restrict__ lpart, const u16* __restrict__ Bt,
                        const float* __restrict__ bias, const float* __restrict__ res,
                        float* __restrict__ Cout) {
    __shared__ u16 Asm[2][64 * GP];
    __shared__ u16 Bsm[2][128 * 32];

    const int tid = threadIdx.x;
    const int w = tid >> 6;
    const int lane = tid & 63;
    const int quad = lane >> 4;
    const int l15 = lane & 15;
    const int row0 = blockIdx.y * 64;
    const int col0 = blockIdx.x * GBN;
    const int rh = (w & 1) * 32;
    const int cg = (w >> 1) * 32;
    const int K = DMODEL;

    f32x4 acc[2][2];
#pragma unroll
    for (int i = 0; i < 2; ++i)
#pragma unroll
        for (int j = 0; j < 2; ++j) acc[i][j] = (f32x4){0.f, 0.f, 0.f, 0.f};

    // B staging via gload_lds
    const int crow = lane >> 2;
    const int ck = (lane & 3) * 8;
    const u16* gB = &Bt[(size_t)(col0 + w * 16 + crow) * K + ck];
    const int lBo = w * 512;

    // A staging (computed): tid<256, reg path
    const int arow = (tid & 255) >> 2, ak = (tid & 3) * 8;
    const bool doA = (tid < 256);

    float linv[8];
    if (doA) {
        // lpart row: 32 floats, layout [sp*8+h], sp=0..3
        const float* lr = lpart + (size_t)(row0 + arow) * 32;
        float ls[8] = {0.f, 0.f, 0.f, 0.f, 0.f, 0.f, 0.f, 0.f};
#pragma unroll
        for (int v = 0; v < 8; ++v) {
            float4 q = *(const float4*)&lr[v * 4];
            ls[(v * 4 + 0) & 7] += q.x;
            ls[(v * 4 + 1) & 7] += q.y;
            ls[(v * 4 + 2) & 7] += q.z;
            ls[(v * 4 + 3) & 7] += q.w;
        }
#pragma unroll
        for (int hh = 0; hh < 8; ++hh) linv[hh] = 1.0f / ls[hh];
    }

    {
        gld16(gB, &Bsm[0][lBo]);
        if (doA) {
            uint4 a0 = reduce4_norm(Ob0, Ob1, (size_t)(row0 + arow) * DMODEL + ak, linv[0]);
            *(uint4*)&Asm[0][arow * GP + ak] = a0;
        }
    }
    __syncthreads();

#pragma unroll
    for (int t = 0; t < 16; ++t) {
        const int buf = t & 1;
        uint4 an;
        if (t + 1 < 16) {
            const int k0 = (t + 1) * GBK;
            gld16(gB + k0, &Bsm[buf ^ 1][lBo]);
            if (doA)
                an = reduce4_norm(Ob0, Ob1, (size_t)(row0 + arow) * DMODEL + k0 + ak,
                                  linv[(t + 1) >> 1]);
        }
        bf16x8 af[2], bf[2];
#pragma unroll
        for (int i = 0; i < 2; ++i)
            af[i] = *(const bf16x8*)&Asm[buf][(rh + i * 16 + l15) * GP + quad * 8];
#pragma unroll
        for (int j = 0; j < 2; ++j)
            bf[j] = *(const bf16x8*)&Bsm[buf][(cg + j * 16 + l15) * 32 + quad * 8];
#pragma unroll
        for (int i = 0; i < 2; ++i)
#pragma unroll
            for (int j = 0; j < 2; ++j)
                acc[i][j] = mfma16(af[i], bf[j], acc[i][j]);
        if (t + 1 < 16) {
            if (doA) *(uint4*)&Asm[buf ^ 1][arow * GP + ak] = an;
            __syncthreads();
        }
    }

#pragma unroll
    for (int j = 0; j < 2; ++j) {
        const int col = col0 + cg + j * 16 + l15;
        const float bc = bias[col];
#pragma unroll
        for (int i = 0; i < 2; ++i) {
#pragma unroll
            for (int r = 0; r < 4; ++r) {
                const int row = row0 + rh + i * 16 + quad * 4 + r;
                Cout[(size_t)row * DMODEL + col] =
                    acc[i][j][r] + bc + res[(size_t)row * DMODEL + col];
            }
        }
    }
}

// ---------------------------------------------------------------------------
// Batched Wg+Q+K+V GEMM, 128x128 tile, 512 thr, acc[2][4], gload_lds.
// ---------------------------------------------------------------------------
#define QSCALE 0.1803368801111204f   // 0.125 * log2(e)

__launch_bounds__(512)
__global__ void qkvg_gemm(const u16* __restrict__ xb, const u16* __restrict__ hb,
                          const u16* __restrict__ Wall,
                          const float* __restrict__ bq, const float* __restrict__ bk,
                          const float* __restrict__ bv,
                          u16* __restrict__ xtb, u16* __restrict__ qkvb,
                          u16* __restrict__ vtb) {
    __shared__ u16 Asm[2][128 * 32];
    __shared__ u16 Bsm[2][128 * 32];

    const int tid = threadIdx.x;
    const int w = tid >> 6;
    const int lane = tid & 63;
    const int quad = lane >> 4;
    const int l15 = lane & 15;
    const int row0 = blockIdx.y * 128;
    const int col0 = blockIdx.x * 128;
    const int rh = (w & 3) * 32;
    const int cg = (w >> 2) * 64;
    const int K = DMODEL;
    const u16* A = (col0 < 512) ? xb : hb;

    f32x4 acc[2][4];
#pragma unroll
    for (int i = 0; i < 2; ++i)
#pragma unroll
        for (int j = 0; j < 4; ++j) acc[i][j] = (f32x4){0.f, 0.f, 0.f, 0.f};

    const int crow = lane >> 2;
    const int ck = (lane & 3) * 8;
    const u16* gA = &A   [(size_t)(row0 + w * 16 + crow) * K + ck];
    const u16* gB = &Wall[(size_t)(col0 + w * 16 + crow) * K + ck];
    const int lo = w * 512;

    gld16(gA, &Asm[0][lo]);
    gld16(gB, &Bsm[0][lo]);
    __syncthreads();

    const int nT = K / GBK;
    for (int t = 0; t < nT; ++t) {
        const int buf = t & 1;
        if (t + 1 < nT) {
            const int k0 = (t + 1) * GBK;
            gld16(gA + k0, &Asm[buf ^ 1][lo]);
            gld16(gB + k0, &Bsm[buf ^ 1][lo]);
        }
        bf16x8 af[2], bf[4];
#pragma unroll
        for (int i = 0; i < 2; ++i)
            af[i] = *(const bf16x8*)&Asm[buf][(rh + i * 16 + l15) * 32 + quad * 8];
#pragma unroll
        for (int j = 0; j < 4; ++j)
            bf[j] = *(const bf16x8*)&Bsm[buf][(cg + j * 16 + l15) * 32 + quad * 8];
#pragma unroll
        for (int i = 0; i < 2; ++i)
#pragma unroll
            for (int j = 0; j < 4; ++j)
                acc[i][j] = mfma16(af[i], bf[j], acc[i][j]);
        if (t + 1 < nT) __syncthreads();
    }

#pragma unroll
    for (int j = 0; j < 4; ++j) {
        const int col = col0 + cg + j * 16 + l15;
        if (col < 512) {
#pragma unroll
            for (int i = 0; i < 2; ++i)
#pragma unroll
                for (int r = 0; r < 4; ++r)
                    xtb[(size_t)(row0 + rh + i * 16 + quad * 4 + r) * 512 + col] =
                        f2bf(acc[i][j][r]);
        } else if (col < 1536) {
            const float bc = (col < 1024) ? bq[col - 512] : bk[col - 1024];
            const float scale = (col < 1024) ? QSCALE : 1.0f;
#pragma unroll
            for (int i = 0; i < 2; ++i)
#pragma unroll
                for (int r = 0; r < 4; ++r)
                    qkvb[(size_t)(row0 + rh + i * 16 + quad * 4 + r) * QKVLD + col - 512] =
                        f2bf((acc[i][j][r] + bc) * scale);
        } else {
            const int hd = col - 1536;
            const float bc = bv[hd];
#pragma unroll
            for (int i = 0; i < 2; ++i) {
                ushort4 pk;
                pk.x = f2bf(acc[i][j][0] + bc);
                pk.y = f2bf(acc[i][j][1] + bc);
                pk.z = f2bf(acc[i][j][2] + bc);
                pk.w = f2bf(acc[i][j][3] + bc);
                *(uint2*)&vtb[(size_t)hd * N_NODES + row0 + rh + i * 16 + quad * 4] =
                    *(uint2*)&pk;
            }
        }
    }
}

// ---------------------------------------------------------------------------
// Fused prep (one launch, 7952 blocks)
// ---------------------------------------------------------------------------
__device__ inline float block_sum_256(float v, float* red4) {
#pragma unroll
    for (int o = 32; o > 0; o >>= 1) v += __shfl_down(v, o, 64);
    const int lane = threadIdx.x & 63;
    const int w = threadIdx.x >> 6;
    if (lane == 0) red4[w] = v;
    __syncthreads();
    return red4[0] + red4[1] + red4[2] + red4[3];
}

__launch_bounds__(256)
__global__ void prep_kernel(
    const float* __restrict__ Wg, const float* __restrict__ Wq,
    const float* __restrict__ Wk, const float* __restrict__ Wv,
    const float* __restrict__ Wo, const float* __restrict__ W1,
    const float* __restrict__ W2, const float* __restrict__ Wa,
    u16* __restrict__ Wgt, u16* __restrict__ Wqt, u16* __restrict__ Wkt,
    u16* __restrict__ Wvt, u16* __restrict__ Wot, u16* __restrict__ W1t,
    u16* __restrict__ W2t, u16* __restrict__ Wat,
    const float* __restrict__ x, u16* __restrict__ xb,
    const float* __restrict__ ln1s, const float* __restrict__ ln1b,
    u16* __restrict__ hb, float* __restrict__ deg, int* __restrict__ cnt) {
    __shared__ u16 t[32][34];
    __shared__ float redA[4];
    __shared__ float redB[4];
    const int id = blockIdx.x;

    if (id < 3840) {
        const float* W; u16* Wt; int K, Nn, bx, by;
        if (id < 1280) {
            const int m = id >> 8, tt = id & 255;
            bx = tt & 15; by = tt >> 4; K = 512; Nn = 512;
            W  = (m == 0) ? Wg  : (m == 1) ? Wq  : (m == 2) ? Wk  : (m == 3) ? Wv  : Wo;
            Wt = (m == 0) ? Wgt : (m == 1) ? Wqt : (m == 2) ? Wkt : (m == 3) ? Wvt : Wot;
        } else if (id < 2304) {
            const int tt = id - 1280; bx = tt & 63; by = tt >> 6;
            K = 512; Nn = 2048; W = W1; Wt = W1t;
        } else if (id < 3328) {
            const int tt = id - 2304; bx = tt & 15; by = tt >> 4;
            K = 2048; Nn = 512; W = W2; Wt = W2t;
        } else {
            const int tt = id - 3328; bx = tt & 15; by = tt >> 4;
            K = 1024; Nn = 512; W = Wa; Wt = Wat;
        }
        const int k0 = by * 32, n0 = bx * 32;
        const int r = threadIdx.x >> 3, c4 = (threadIdx.x & 7) * 4;
        float4 v = *(const float4*)&W[(size_t)(k0 + r) * Nn + n0 + c4];
        t[r][c4 + 0] = f2bf(v.x); t[r][c4 + 1] = f2bf(v.y);
        t[r][c4 + 2] = f2bf(v.z); t[r][c4 + 3] = f2bf(v.w);
        __syncthreads();
        u16 tmp[4];
#pragma unroll
        for (int i = 0; i < 4; ++i) tmp[i] = t[c4 + i][r];
        u16* op = Wt + (size_t)(n0 + r) * K + k0 + c4;
        *(uint2*)op = *(uint2*)tmp;
    } else if (id < 7936) {
        const int row = id - 3840;
        const int tid = threadIdx.x;
        const float* xr = x + (size_t)row * DMODEL;
        float v0 = xr[tid], v1 = xr[tid + 256];
        xb[(size_t)row * DMODEL + tid] = f2bf(v0);
        xb[(size_t)row * DMODEL + tid + 256] = f2bf(v1);
        float total = block_sum_256(v0 + v1, redA);
        float mean = total * (1.0f / DMODEL);
        float d0 = v0 - mean, d1 = v1 - mean;
        float sq = block_sum_256(d0 * d0 + d1 * d1, redB);
        float inv = rsqrtf(sq * (1.0f / DMODEL) + 1e-5f);
        hb[(size_t)row * DMODEL + tid] = f2bf(d0 * inv * ln1s[tid] + ln1b[tid]);
        hb[(size_t)row * DMODEL + tid + 256] =
            f2bf(d1 * inv * ln1s[tid + 256] + ln1b[tid + 256]);
    } else {
        int i = (id - 7936) * 256 + threadIdx.x;
        deg[i] = 1.0f;
        cnt[i] = 0;
    }
}

// ---------------------------------------------------------------------------
// LayerNorm (standalone, for ln2)
// ---------------------------------------------------------------------------
__launch_bounds__(256)
__global__ void ln_kernel(const float* __restrict__ X, const float* __restrict__ s,
                          const float* __restrict__ b, u16* __restrict__ Y) {
    __shared__ float redA[4];
    __shared__ float redB[4];
    const int row = blockIdx.x;
    const int tid = threadIdx.x;
    const float* xr = X + (size_t)row * DMODEL;
    float v0 = xr[tid], v1 = xr[tid + 256];
    float total = block_sum_256(v0 + v1, redA);
    float mean = total * (1.0f / DMODEL);
    float d0 = v0 - mean, d1 = v1 - mean;
    float sq = block_sum_256(d0 * d0 + d1 * d1, redB);
    float inv = rsqrtf(sq * (1.0f / DMODEL) + 1e-5f);
    Y[(size_t)row * DMODEL + tid] = f2bf(d0 * inv * s[tid] + b[tid]);
    Y[(size_t)row * DMODEL + tid + 256] = f2bf(d1 * inv * s[tid + 256] + b[tid + 256]);
}

// ---------------------------------------------------------------------------
// GCN CSR build: count + prefix + fill in ONE cooperative launch.
// Grid 256 x 256 thr = 65536 threads = 1 edge/thread. Block 0 runs the
// prefix scan between grid syncs (others wait). Replaces 3 kernels.
// ---------------------------------------------------------------------------
__launch_bounds__(256)
__global__ void gcn_build_kernel(const int* __restrict__ ei, const float* __restrict__ ew,
                                 float* __restrict__ deg, int* __restrict__ cnt,
                                 int* __restrict__ off, int* __restrict__ cur,
                                 int* __restrict__ esrc, float* __restrict__ eww,
                                 float* __restrict__ dinv) {
    cg::grid_group grid = cg::this_grid();
    const int e = blockIdx.x * 256 + threadIdx.x;
    const int s = ei[e];
    const int d = ei[NEDGE + e];
    const float wgt = ew[e];
    atomicAdd(&cnt[d], 1);
    atomicAdd(&deg[d], wgt);

    grid.sync();

    if (blockIdx.x == 0) {
        __shared__ int part[256];
        const int tid = threadIdx.x;
        int local[16];
        int acc = 0;
#pragma unroll
        for (int i = 0; i < 16; ++i) { local[i] = acc; acc += cnt[tid * 16 + i]; }
        part[tid] = acc;
#pragma unroll
        for (int i = 0; i < 16; ++i) {
            const int n = tid * 16 + i;
            float dd = deg[n];
            dinv[n] = (dd > 0.f) ? rsqrtf(fmaxf(dd, 1e-12f)) : 0.f;
        }
        __syncthreads();
        if (tid == 0) {
            int run = 0;
            for (int j = 0; j < 256; ++j) { int t = part[j]; part[j] = run; run += t; }
            off[N_NODES] = run;
        }
        __syncthreads();
        int p = part[tid];
#pragma unroll
        for (int i = 0; i < 16; ++i) {
            off[tid * 16 + i] = p + local[i];
            cur[tid * 16 + i] = p + local[i];
        }
    }

    grid.sync();

    const int pos = atomicAdd(&cur[d], 1);
    esrc[pos] = s;
    eww[pos] = wgt;
}

__launch_bounds__(256)
__global__ void gcn_gather_kernel(const u16* __restrict__ xtb, const int* __restrict__ off,
                                  const int* __restrict__ esrc, const float* __restrict__ eww,
                                  const float* __restrict__ dinv, const float* __restrict__ bg,
                                  u16* __restrict__ catb) {
    const int d = blockIdx.x;
    const int b0 = off[d], b1 = off[d + 1];
    const float did = dinv[d];
    const int c = threadIdx.x * 2;
    float a0 = 0.f, a1 = 0.f;
    for (int j = b0; j < b1; ++j) {
        const int s = esrc[j];
        const float coef = dinv[s] * eww[j] * did;
        const unsigned pv = *(const unsigned*)&xtb[(size_t)s * DMODEL + c];
        a0 += coef * bf2f((u16)(pv & 0xffff));
        a1 += coef * bf2f((u16)(pv >> 16));
    }
    {
        const unsigned pv = *(const unsigned*)&xtb[(size_t)d * DMODEL + c];
        const float sl = did * did;
        a0 += sl * bf2f((u16)(pv & 0xffff));
        a1 += sl * bf2f((u16)(pv >> 16));
    }
    const unsigned pk = (unsigned)f2bf(a0 + bg[c]) | ((unsigned)f2bf(a1 + bg[c + 1]) << 16);
    *(unsigned*)&catb[(size_t)d * 1024 + c] = pk;
}

// ---------------------------------------------------------------------------
// MFMA flash attention. TQ=256 rows/block (64/wave, a=0..3), K-SPLIT x4.
// Double-buffered K/V, register-cached K/V frags, no setprio (R9 win).
// ---------------------------------------------------------------------------
#define TK 64
#define AP 72
#define NSPLIT 4
#define KSPAN (N_NODES / NSPLIT)
#define TQ 256

__launch_bounds__(256, 2)
__global__ void attn_kernel(const u16* __restrict__ Qkv, const u16* __restrict__ Vtb,
                            u16* __restrict__ Ob0, u16* __restrict__ Ob1,
                            float* __restrict__ lpart) {
    __shared__ u16 Ks[2][64 * AP];
    __shared__ u16 Vs[2][64 * AP];

    const int h = blockIdx.x;
    const int q0 = blockIdx.y * TQ;
    const int sp = blockIdx.z;
    u16* __restrict__ Opx = ((sp < 2) ? Ob0 : Ob1) + (size_t)(sp & 1) * N_NODES * DMODEL;
    const int kbase = sp * KSPAN;

    const int tid = threadIdx.x;
    const int w = tid >> 6;
    const int lane = tid & 63;
    const int quad = lane >> 4;
    const int l15 = lane & 15;

    // Q fragments: 4 a-blocks of 16 rows each (wave rows q0 + w*64 .. +63)
    const u16* qp = Qkv + (size_t)(q0 + w * 64 + l15) * QKVLD + h * DHEAD + quad * 8;
    bf16x8 qf[4][2];
#pragma unroll
    for (int a = 0; a < 4; ++a) {
        qf[a][0] = *(const bf16x8*)(qp + (size_t)a * 16 * QKVLD);
        qf[a][1] = *(const bf16x8*)(qp + (size_t)a * 16 * QKVLD + 32);
    }

    f32x4 Oa[4][4];
#pragma unroll
    for (int a = 0; a < 4; ++a)
#pragma unroll
        for (int g = 0; g < 4; ++g) Oa[a][g] = (f32x4){0.f, 0.f, 0.f, 0.f};
    float ls[4] = {0.f, 0.f, 0.f, 0.f};

    const int srow = (tid & 127) >> 1;
    const int scol = (tid & 1) * 32;
    const bool isK = (tid < 128);

    // prologue: stage tile 0 into buffer 0
    {
        if (isK) {
            const uint4* kg = (const uint4*)(Qkv + (size_t)(kbase + srow) * QKVLD + 512 + h * DHEAD + scol);
            uint4* kd = (uint4*)&Ks[0][srow * AP + scol];
            kd[0] = kg[0]; kd[1] = kg[1]; kd[2] = kg[2]; kd[3] = kg[3];
        } else {
            const uint4* vg = (const uint4*)(Vtb + ((size_t)h * DHEAD + srow) * N_NODES + kbase + scol);
            uint4* vd = (uint4*)&Vs[0][srow * AP + scol];
            vd[0] = vg[0]; vd[1] = vg[1]; vd[2] = vg[2]; vd[3] = vg[3];
        }
    }
    __syncthreads();

    const int NT = KSPAN / TK;   // 16
    for (int t = 0; t < NT; ++t) {
        const int buf = t & 1;
        const bool more = (t + 1 < NT);
        uint4 s0, s1, s2, s3;
        if (more) {
            // issue next-tile global loads EARLY; latency hides under compute
            const int kn = kbase + (t + 1) * TK;
            if (isK) {
                const uint4* kg = (const uint4*)(Qkv + (size_t)(kn + srow) * QKVLD + 512 + h * DHEAD + scol);
                s0 = kg[0]; s1 = kg[1]; s2 = kg[2]; s3 = kg[3];
            } else {
                const uint4* vg = (const uint4*)(Vtb + ((size_t)h * DHEAD + srow) * N_NODES + kn + scol);
                s0 = vg[0]; s1 = vg[1]; s2 = vg[2]; s3 = vg[3];
            }
        }

        // LDS -> register fragments (reused across all 4 a-blocks)
        bf16x8 kf0[4], kf1[4];
#pragma unroll
        for (int f = 0; f < 4; ++f) {
            const u16* kr = &Ks[buf][(f * 16 + l15) * AP + quad * 8];
            kf0[f] = *(const bf16x8*)kr;
            kf1[f] = *(const bf16x8*)(kr + 32);
        }
        s16x4 vv[4][4];
#pragma unroll
        for (int g = 0; g < 4; ++g)
#pragma unroll
            for (int f = 0; f < 4; ++f)
                vv[f][g] = *(const s16x4*)&Vs[buf][(g * 16 + l15) * AP + f * 16 + quad * 4];

#pragma unroll
        for (int a = 0; a < 4; ++a) {
            f32x4 St[4];
#pragma unroll
            for (int f = 0; f < 4; ++f) {
                f32x4 z = (f32x4){0.f, 0.f, 0.f, 0.f};
                z = mfma16(kf0[f], qf[a][0], z);
                St[f] = mfma16(kf1[f], qf[a][1], z);
            }
            s16x4 pk[4];
#pragma unroll
            for (int f = 0; f < 4; ++f) {
                f32x4 p;
                p[0] = fast_exp2(St[f][0]);
                p[1] = fast_exp2(St[f][1]);
                p[2] = fast_exp2(St[f][2]);
                p[3] = fast_exp2(St[f][3]);
                ls[a] += (p[0] + p[1]) + (p[2] + p[3]);
                pk[f] = pack_bf4(p);
            }
#pragma unroll
            for (int f = 0; f < 4; ++f)
#pragma unroll
                for (int g = 0; g < 4; ++g)
                    Oa[a][g] = mfma1k(pk[f], vv[f][g], Oa[a][g]);
        }

        if (more) {
            // write-late: lands in the other buffer after compute on this one
            if (isK) {
                uint4* kd = (uint4*)&Ks[buf ^ 1][srow * AP + scol];
                kd[0] = s0; kd[1] = s1; kd[2] = s2; kd[3] = s3;
            } else {
                uint4* vd = (uint4*)&Vs[buf ^ 1][srow * AP + scol];
                vd[0] = s0; vd[1] = s1; vd[2] = s2; vd[3] = s3;
            }
            __syncthreads();
        }
    }

#pragma unroll
    for (int a = 0; a < 4; ++a) {
        float s = ls[a];
        s += __shfl_xor(s, 16, 64);
        s += __shfl_xor(s, 32, 64);
        const int rowbase = q0 + w * 64 + a * 16;
        if (quad == 0)
            lpart[(size_t)(rowbase + l15) * 32 + sp * 8 + h] = s;
#pragma unroll
        for (int r = 0; r < 4; ++r) {
            u16* op = Opx + (size_t)(rowbase + quad * 4 + r) * DMODEL + h * DHEAD + l15;
#pragma unroll
            for (int g = 0; g < 4; ++g) op[g * 16] = f2bf(Oa[a][g][r]);
        }
    }
}

// ---------------------------------------------------------------------------
// host side
// ---------------------------------------------------------------------------
static void mgemm64(hipStream_t st, const u16* A, const u16* Bt, const float* bias,
                    const float* res, void* C, int M, int Nn, int K, float scale,
                    int act, int obf16, int ldC, int ldRes) {
    dim3 g(Nn / GBN, M / 64), b(512);
    if (act)
        hipLaunchKernelGGL((mfma_gemm64<1, 1>), g, b, 0, st, A, Bt, bias, res, C, M, Nn, K, scale, ldC, ldRes);
    else if (obf16)
        hipLaunchKernelGGL((mfma_gemm64<0, 1>), g, b, 0, st, A, Bt, bias, res, C, M, Nn, K, scale, ldC, ldRes);
    else
        hipLaunchKernelGGL((mfma_gemm64<0, 0>), g, b, 0, st, A, Bt, bias, res, C, M, Nn, K, scale, ldC, ldRes);
}

extern "C" void kernel_launch(void* const* d_in, const int* in_sizes, int n_in,
                              void* d_out, int out_size, void* d_ws, size_t ws_size,
                              hipStream_t stream) {
    const float* x    = (const float*)d_in[0];
    const int*   ei   = (const int*)d_in[1];
    const float* ew   = (const float*)d_in[2];
    const float* Wg   = (const float*)d_in[3];
    const float* bg   = (const float*)d_in[4];
    const float* ln1s = (const float*)d_in[5];
    const float* ln1b = (const float*)d_in[6];
    const float* Wq   = (const float*)d_in[7];
    const float* bq   = (const float*)d_in[8];
    const float* Wk   = (const float*)d_in[9];
    const float* bk   = (const float*)d_in[10];
    const float* Wv   = (const float*)d_in[11];
    const float* bv   = (const float*)d_in[12];
    const float* Wo   = (const float*)d_in[13];
    const float* bo   = (const float*)d_in[14];
    const float* ln2s = (const float*)d_in[15];
    const float* ln2b = (const float*)d_in[16];
    const float* W1   = (const float*)d_in[17];
    const float* b1   = (const float*)d_in[18];
    const float* W2   = (const float*)d_in[19];
    const float* b2   = (const float*)d_in[20];
    const float* Wa   = (const float*)d_in[21];
    const float* ba   = (const float*)d_in[22];
    float* out = (float*)d_out;
    float* ws  = (float*)d_ws;

    const size_t SLOT = (size_t)N_NODES * DMODEL;  // 2M floats = 8 MB

    u16* xtb = (u16*)ws;
    u16* Ob0 = (u16*)ws;               // splits 0,1 (after gather consumes xtb)
    float* lpart = ws + SLOT;          // [4096][32] fp32 = 512 KB
    int*   esrc  = (int*)(ws + SLOT + 327680);
    float* eww   = (float*)(esrc + NEDGE);
    int*   off   = (int*)(eww + NEDGE);
    int*   cur   = off + 4100;
    int*   cnt   = cur + 4096;
    u16* Ob1 = (u16*)(ws + 2 * SLOT);  // splits 2,3
    u16* hb  = (u16*)(ws + 3 * SLOT);
    u16* h2b = hb + SLOT;
    u16*   qkvb = (u16*)(ws + 4 * SLOT);
    float* x1   = ws + 4 * SLOT;
    u16*   vtb  = (u16*)(ws + 5 * SLOT) + SLOT;
    u16* midb = (u16*)(ws + 6 * SLOT);
    u16* catb = (u16*)(ws + 8 * SLOT);
    u16* xb   = catb;
    u16* Wgt = (u16*)(ws + 9 * SLOT);
    u16* Wqt = Wgt + 262144;
    u16* Wkt = Wqt + 262144;
    u16* Wvt = Wkt + 262144;
    u16* Wot = Wvt + 262144;
    u16* W1t = Wot + 262144;
    u16* W2t = W1t + 1048576;
    u16* Wat = W2t + 1048576;
    float* deg  = (float*)(Wat + 524288);
    float* dinv = deg + N_NODES;

    hipLaunchKernelGGL(prep_kernel, dim3(7952), dim3(256), 0, stream,
                       Wg, Wq, Wk, Wv, Wo, W1, W2, Wa,
                       Wgt, Wqt, Wkt, Wvt, Wot, W1t, W2t, Wat,
                       x, xb, ln1s, ln1b, hb, deg, cnt);

    hipLaunchKernelGGL(qkvg_gemm, dim3(16, 32), dim3(512), 0, stream,
                       xb, hb, Wgt, bq, bk, bv, xtb, qkvb, vtb);

    // fused CSR build (count + prefix + fill) in one cooperative launch
    {
        void* args[] = {(void*)&ei, (void*)&ew, (void*)&deg, (void*)&cnt,
                        (void*)&off, (void*)&cur, (void*)&esrc, (void*)&eww,
                        (void*)&dinv};
        hipLaunchCooperativeKernel((const void*)gcn_build_kernel,
                                   dim3(256), dim3(256), args, 0, stream);
    }
    hipLaunchKernelGGL(gcn_gather_kernel, dim3(N_NODES), dim3(256), 0, stream,
                       xtb, off, esrc, eww, dinv, bg, catb);

    hipLaunchKernelGGL(attn_kernel, dim3(NHEAD, N_NODES / TQ, NSPLIT), dim3(256), 0, stream,
                       qkvb, vtb, Ob0, Ob1, lpart);

    hipLaunchKernelGGL(wo_gemm, dim3(4, 64), dim3(512), 0, stream,
                       Ob0, Ob1, lpart, Wot, bo, x, x1);

    hipLaunchKernelGGL(ln_kernel, dim3(N_NODES), dim3(256), 0, stream, x1, ln2s, ln2b, h2b);
    // W1: 128x128-tile (grid 16x32 = 512 blocks)
    hipLaunchKernelGGL((mfma_gemm128<1, 1>), dim3(DFF / 128, N_NODES / 128), dim3(512), 0, stream,
                       h2b, W1t, b1, nullptr, midb, N_NODES, DFF, DMODEL, 1.0f, DFF, DFF);
    mgemm64(stream, midb, W2t, b2, x1, catb + 512, N_NODES, DMODEL, DFF, 1.0f, 0, 1, 1024, DMODEL);

    mgemm64(stream, catb, Wat, ba, x, out, N_NODES, DMODEL, 2 * DMODEL, 1.0f, 0, 0, DMODEL, DMODEL);
}

// Round 12
// 311.283 us; speedup vs baseline: 1.2699x; 1.2699x over previous
//
#include <hip/hip_runtime.h>
#include <math.h>

#define N_NODES 4096
#define DMODEL  512
#define NHEAD   8
#define DHEAD   64
#define DFF     2048
#define NEDGE   65536
#define QKVLD   1536

typedef unsigned short u16;
typedef __bf16 bf16x8 __attribute__((ext_vector_type(8)));
typedef float  f32x4  __attribute__((ext_vector_type(4)));
typedef short  s16x4  __attribute__((ext_vector_type(4)));

#if defined(__has_builtin)
#if __has_builtin(__builtin_amdgcn_mfma_f32_16x16x16bf16_1k)
#define HAS_MFMA_1K 1
#endif
#if __has_builtin(__builtin_amdgcn_global_load_lds)
#define HAS_GLOAD_LDS 1
#endif
#endif

__device__ inline float fast_exp2(float x) {
    return __builtin_amdgcn_exp2f(x);   // v_exp_f32: 2^x native
}

__device__ inline f32x4 mfma16(bf16x8 a, bf16x8 b, f32x4 c) {
    return __builtin_amdgcn_mfma_f32_16x16x32_bf16(a, b, c, 0, 0, 0);
}

__device__ inline u16 f2bf(float f) {  // RNE
    union { float f; unsigned u; } v; v.f = f;
    unsigned r = v.u + 0x7fff + ((v.u >> 16) & 1);
    return (u16)(r >> 16);
}

#ifdef HAS_MFMA_1K
__device__ inline f32x4 mfma1k(s16x4 a, s16x4 b, f32x4 c) {
    return __builtin_amdgcn_mfma_f32_16x16x16bf16_1k(a, b, c, 0, 0, 0);
}
__device__ inline s16x4 pack_bf4(f32x4 p) {
    union { float f; unsigned u; } a0, a1, a2, a3;
    a0.f = p[0]; a1.f = p[1]; a2.f = p[2]; a3.f = p[3];
    unsigned lo = __builtin_amdgcn_perm(a1.u + 0x8000u, a0.u + 0x8000u, 0x07060302u);
    unsigned hi = __builtin_amdgcn_perm(a3.u + 0x8000u, a2.u + 0x8000u, 0x07060302u);
    union { unsigned u[2]; s16x4 v; } r;
    r.u[0] = lo; r.u[1] = hi;
    return r.v;
}
#else
// Host-pass stubs: gfx950 device pass always defines HAS_MFMA_1K. Parsed, never executed.
__device__ inline f32x4 mfma1k(s16x4 a, s16x4 b, f32x4 c) { return c; }
__device__ inline s16x4 pack_bf4(f32x4 p) {
    union { u16 u[4]; s16x4 v; } r;
    r.u[0] = f2bf(p[0]); r.u[1] = f2bf(p[1]); r.u[2] = f2bf(p[2]); r.u[3] = f2bf(p[3]);
    return r.v;
}
#endif

// async global->LDS, 16B/lane. LDS dest is wave-uniform base + lane*16 (linear!).
__device__ inline void gld16(const u16* g, u16* l) {
#ifdef HAS_GLOAD_LDS
    __builtin_amdgcn_global_load_lds((const __attribute__((address_space(1))) void*)g,
                                     (__attribute__((address_space(3))) void*)l,
                                     16, 0, 0);
#else
    // host-parse stub; device pass on gfx950 always takes the builtin path.
    *(uint4*)l = *(const uint4*)g;
#endif
}

__device__ inline float bf2f(u16 v) {
    union { unsigned u; float f; } t; t.u = ((unsigned)v) << 16; return t.f;
}

__device__ inline float gelu_tanh(float x) {
    float x3 = x * x * x;
    float t = tanhf(0.7978845608028654f * (x + 0.044715f * x3));
    return 0.5f * x * (1.0f + t);
}

#define GBN 128
#define GBK 32
#define GP  40

// ---------------------------------------------------------------------------
// MFMA bf16 GEMM 64x128x32, 512 threads = 8 waves, double-buffered via
// global_load_lds (16B/lane, linear LDS [rows][32]). (W2, Wa)
// ---------------------------------------------------------------------------
template <int ACT, int OBF16>
__launch_bounds__(512)
__global__ void mfma_gemm64(const u16* __restrict__ A, const u16* __restrict__ Bt,
                            const float* __restrict__ bias, const float* __restrict__ res,
                            void* __restrict__ Cout, int M, int Nn, int K, float scale,
                            int ldC, int ldRes) {
    __shared__ u16 Asm[2][64 * 32];
    __shared__ u16 Bsm[2][128 * 32];

    const int tid = threadIdx.x;
    const int w = tid >> 6;
    const int lane = tid & 63;
    const int quad = lane >> 4;
    const int l15 = lane & 15;
    const int row0 = blockIdx.y * 64;
    const int col0 = blockIdx.x * GBN;
    const int rh = (w & 1) * 32;
    const int cg = (w >> 1) * 32;

    f32x4 acc[2][2];
#pragma unroll
    for (int i = 0; i < 2; ++i)
#pragma unroll
        for (int j = 0; j < 2; ++j) acc[i][j] = (f32x4){0.f, 0.f, 0.f, 0.f};

    const int crow = lane >> 2;
    const int ck = (lane & 3) * 8;
    const u16* gB = &Bt[(size_t)(col0 + w * 16 + crow) * K + ck];
    const u16* gA = &A [(size_t)(row0 + (w & 3) * 16 + crow) * K + ck];
    const int lBo = w * 512;
    const int lAo = (w & 3) * 512;

    gld16(gB, &Bsm[0][lBo]);
    if (w < 4) gld16(gA, &Asm[0][lAo]);
    __syncthreads();

    const int nT = K / GBK;
    for (int t = 0; t < nT; ++t) {
        const int buf = t & 1;
        if (t + 1 < nT) {
            const int k0 = (t + 1) * GBK;
            gld16(gB + k0, &Bsm[buf ^ 1][lBo]);
            if (w < 4) gld16(gA + k0, &Asm[buf ^ 1][lAo]);
        }
        bf16x8 af[2], bf[2];
#pragma unroll
        for (int i = 0; i < 2; ++i)
            af[i] = *(const bf16x8*)&Asm[buf][(rh + i * 16 + l15) * 32 + quad * 8];
#pragma unroll
        for (int j = 0; j < 2; ++j)
            bf[j] = *(const bf16x8*)&Bsm[buf][(cg + j * 16 + l15) * 32 + quad * 8];
#pragma unroll
        for (int i = 0; i < 2; ++i)
#pragma unroll
            for (int j = 0; j < 2; ++j)
                acc[i][j] = mfma16(af[i], bf[j], acc[i][j]);
        if (t + 1 < nT) __syncthreads();
    }

#pragma unroll
    for (int j = 0; j < 2; ++j) {
        const int col = col0 + cg + j * 16 + l15;
        const float bc = bias ? bias[col] : 0.f;
#pragma unroll
        for (int i = 0; i < 2; ++i) {
#pragma unroll
            for (int r = 0; r < 4; ++r) {
                const int row = row0 + rh + i * 16 + quad * 4 + r;
                float o = (acc[i][j][r] + bc) * scale;
                if (ACT == 1) o = gelu_tanh(o);
                if (res) o += res[(size_t)row * ldRes + col];
                if (OBF16)
                    ((u16*)Cout)[(size_t)row * ldC + col] = f2bf(o);
                else
                    ((float*)Cout)[(size_t)row * ldC + col] = o;
            }
        }
    }
}

// ---------------------------------------------------------------------------
// MFMA bf16 GEMM 128x128x32, 512 threads = 8 waves, acc[2][4] per wave,
// gload_lds staging, double-buffered. (W1)
// ---------------------------------------------------------------------------
template <int ACT, int OBF16>
__launch_bounds__(512)
__global__ void mfma_gemm128(const u16* __restrict__ A, const u16* __restrict__ Bt,
                             const float* __restrict__ bias, const float* __restrict__ res,
                             void* __restrict__ Cout, int M, int Nn, int K, float scale,
                             int ldC, int ldRes) {
    __shared__ u16 Asm[2][128 * 32];
    __shared__ u16 Bsm[2][128 * 32];

    const int tid = threadIdx.x;
    const int w = tid >> 6;
    const int lane = tid & 63;
    const int quad = lane >> 4;
    const int l15 = lane & 15;
    const int row0 = blockIdx.y * 128;
    const int col0 = blockIdx.x * 128;
    const int rh = (w & 3) * 32;
    const int cg = (w >> 2) * 64;

    f32x4 acc[2][4];
#pragma unroll
    for (int i = 0; i < 2; ++i)
#pragma unroll
        for (int j = 0; j < 4; ++j) acc[i][j] = (f32x4){0.f, 0.f, 0.f, 0.f};

    const int crow = lane >> 2;
    const int ck = (lane & 3) * 8;
    const u16* gA = &A [(size_t)(row0 + w * 16 + crow) * K + ck];
    const u16* gB = &Bt[(size_t)(col0 + w * 16 + crow) * K + ck];
    const int lo = w * 512;

    gld16(gA, &Asm[0][lo]);
    gld16(gB, &Bsm[0][lo]);
    __syncthreads();

    const int nT = K / GBK;
    for (int t = 0; t < nT; ++t) {
        const int buf = t & 1;
        if (t + 1 < nT) {
            const int k0 = (t + 1) * GBK;
            gld16(gA + k0, &Asm[buf ^ 1][lo]);
            gld16(gB + k0, &Bsm[buf ^ 1][lo]);
        }
        bf16x8 af[2], bf[4];
#pragma unroll
        for (int i = 0; i < 2; ++i)
            af[i] = *(const bf16x8*)&Asm[buf][(rh + i * 16 + l15) * 32 + quad * 8];
#pragma unroll
        for (int j = 0; j < 4; ++j)
            bf[j] = *(const bf16x8*)&Bsm[buf][(cg + j * 16 + l15) * 32 + quad * 8];
#pragma unroll
        for (int i = 0; i < 2; ++i)
#pragma unroll
            for (int j = 0; j < 4; ++j)
                acc[i][j] = mfma16(af[i], bf[j], acc[i][j]);
        if (t + 1 < nT) __syncthreads();
    }

#pragma unroll
    for (int j = 0; j < 4; ++j) {
        const int col = col0 + cg + j * 16 + l15;
        const float bc = bias ? bias[col] : 0.f;
#pragma unroll
        for (int i = 0; i < 2; ++i) {
#pragma unroll
            for (int r = 0; r < 4; ++r) {
                const int row = row0 + rh + i * 16 + quad * 4 + r;
                float o = (acc[i][j][r] + bc) * scale;
                if (ACT == 1) o = gelu_tanh(o);
                if (res) o += res[(size_t)row * ldRes + col];
                if (OBF16)
                    ((u16*)Cout)[(size_t)row * ldC + col] = f2bf(o);
                else
                    ((float*)Cout)[(size_t)row * ldC + col] = o;
            }
        }
    }
}

// ---------------------------------------------------------------------------
// Fused Wo GEMM with on-the-fly attention split-reduce in the A path.
// NSPLIT=4: slices in Ob0 (sp 0,1) and Ob1 (sp 2,3). 512 thr.
// B via global_load_lds (linear [128][32]); A computed -> reg-staged (GP=40).
// ---------------------------------------------------------------------------
__device__ inline uint4 reduce4_norm(const u16* b0, const u16* b1, size_t off, float linv) {
    const size_t OFF = (size_t)N_NODES * DMODEL;
    float s[8] = {0.f, 0.f, 0.f, 0.f, 0.f, 0.f, 0.f, 0.f};
    const u16* bs[2] = {b0, b1};
#pragma unroll
    for (int b = 0; b < 2; ++b)
#pragma unroll
        for (int k = 0; k < 2; ++k) {
            uint4 v = *(const uint4*)(bs[b] + k * OFF + off);
            unsigned uu[4] = {v.x, v.y, v.z, v.w};
#pragma unroll
            for (int t = 0; t < 4; ++t) {
                s[2 * t]     += bf2f((u16)(uu[t] & 0xffff));
                s[2 * t + 1] += bf2f((u16)(uu[t] >> 16));
            }
        }
    uint4 r;
    r.x = (unsigned)f2bf(s[0] * linv) | ((unsigned)f2bf(s[1] * linv) << 16);
    r.y = (unsigned)f2bf(s[2] * linv) | ((unsigned)f2bf(s[3] * linv) << 16);
    r.z = (unsigned)f2bf(s[4] * linv) | ((unsigned)f2bf(s[5] * linv) << 16);
    r.w = (unsigned)f2bf(s[6] * linv) | ((unsigned)f2bf(s[7] * linv) << 16);
    return r;
}

__launch_bounds__(512)
__global__ void wo_gemm(const u16* __restrict__ Ob0, const u16* __restrict__ Ob1,
                        const float* __restrict__ lpart, const u16* __restrict__ Bt,
                        const float* __restrict__ bias, const float* __restrict__ res,
                        float* __restrict__ Cout) {
    __shared__ u16 Asm[2][64 * GP];
    __shared__ u16 Bsm[2][128 * 32];

    const int tid = threadIdx.x;
    const int w = tid >> 6;
    const int lane = tid & 63;
    const int quad = lane >> 4;
    const int l15 = lane & 15;
    const int row0 = blockIdx.y * 64;
    const int col0 = blockIdx.x * GBN;
    const int rh = (w & 1) * 32;
    const int cg = (w >> 1) * 32;
    const int K = DMODEL;

    f32x4 acc[2][2];
#pragma unroll
    for (int i = 0; i < 2; ++i)
#pragma unroll
        for (int j = 0; j < 2; ++j) acc[i][j] = (f32x4){0.f, 0.f, 0.f, 0.f};

    // B staging via gload_lds
    const int crow = lane >> 2;
    const int ck = (lane & 3) * 8;
    const u16* gB = &Bt[(size_t)(col0 + w * 16 + crow) * K + ck];
    const int lBo = w * 512;

    // A staging (computed): tid<256, reg path
    const int arow = (tid & 255) >> 2, ak = (tid & 3) * 8;
    const bool doA = (tid < 256);

    float linv[8];
    if (doA) {
        // lpart row: 32 floats, layout [sp*8+h], sp=0..3
        const float* lr = lpart + (size_t)(row0 + arow) * 32;
        float ls[8] = {0.f, 0.f, 0.f, 0.f, 0.f, 0.f, 0.f, 0.f};
#pragma unroll
        for (int v = 0; v < 8; ++v) {
            float4 q = *(const float4*)&lr[v * 4];
            ls[(v * 4 + 0) & 7] += q.x;
            ls[(v * 4 + 1) & 7] += q.y;
            ls[(v * 4 + 2) & 7] += q.z;
            ls[(v * 4 + 3) & 7] += q.w;
        }
#pragma unroll
        for (int hh = 0; hh < 8; ++hh) linv[hh] = 1.0f / ls[hh];
    }

    {
        gld16(gB, &Bsm[0][lBo]);
        if (doA) {
            uint4 a0 = reduce4_norm(Ob0, Ob1, (size_t)(row0 + arow) * DMODEL + ak, linv[0]);
            *(uint4*)&Asm[0][arow * GP + ak] = a0;
        }
    }
    __syncthreads();

#pragma unroll
    for (int t = 0; t < 16; ++t) {
        const int buf = t & 1;
        uint4 an;
        if (t + 1 < 16) {
            const int k0 = (t + 1) * GBK;
            gld16(gB + k0, &Bsm[buf ^ 1][lBo]);
            if (doA)
                an = reduce4_norm(Ob0, Ob1, (size_t)(row0 + arow) * DMODEL + k0 + ak,
                                  linv[(t + 1) >> 1]);
        }
        bf16x8 af[2], bf[2];
#pragma unroll
        for (int i = 0; i < 2; ++i)
            af[i] = *(const bf16x8*)&Asm[buf][(rh + i * 16 + l15) * GP + quad * 8];
#pragma unroll
        for (int j = 0; j < 2; ++j)
            bf[j] = *(const bf16x8*)&Bsm[buf][(cg + j * 16 + l15) * 32 + quad * 8];
#pragma unroll
        for (int i = 0; i < 2; ++i)
#pragma unroll
            for (int j = 0; j < 2; ++j)
                acc[i][j] = mfma16(af[i], bf[j], acc[i][j]);
        if (t + 1 < 16) {
            if (doA) *(uint4*)&Asm[buf ^ 1][arow * GP + ak] = an;
            __syncthreads();
        }
    }

#pragma unroll
    for (int j = 0; j < 2; ++j) {
        const int col = col0 + cg + j * 16 + l15;
        const float bc = bias[col];
#pragma unroll
        for (int i = 0; i < 2; ++i) {
#pragma unroll
            for (int r = 0; r < 4; ++r) {
                const int row = row0 + rh + i * 16 + quad * 4 + r;
                Cout[(size_t)row * DMODEL + col] =
                    acc[i][j][r] + bc + res[(size_t)row * DMODEL + col];
            }
        }
    }
}

// ---------------------------------------------------------------------------
// Batched Wg+Q+K+V GEMM, 128x128 tile, 512 thr, acc[2][4], gload_lds.
// ---------------------------------------------------------------------------
#define QSCALE 0.1803368801111204f   // 0.125 * log2(e)

__launch_bounds__(512)
__global__ void qkvg_gemm(const u16* __restrict__ xb, const u16* __restrict__ hb,
                          const u16* __restrict__ Wall,
                          const float* __restrict__ bq, const float* __restrict__ bk,
                          const float* __restrict__ bv,
                          u16* __restrict__ xtb, u16* __restrict__ qkvb,
                          u16* __restrict__ vtb) {
    __shared__ u16 Asm[2][128 * 32];
    __shared__ u16 Bsm[2][128 * 32];

    const int tid = threadIdx.x;
    const int w = tid >> 6;
    const int lane = tid & 63;
    const int quad = lane >> 4;
    const int l15 = lane & 15;
    const int row0 = blockIdx.y * 128;
    const int col0 = blockIdx.x * 128;
    const int rh = (w & 3) * 32;
    const int cg = (w >> 2) * 64;
    const int K = DMODEL;
    const u16* A = (col0 < 512) ? xb : hb;

    f32x4 acc[2][4];
#pragma unroll
    for (int i = 0; i < 2; ++i)
#pragma unroll
        for (int j = 0; j < 4; ++j) acc[i][j] = (f32x4){0.f, 0.f, 0.f, 0.f};

    const int crow = lane >> 2;
    const int ck = (lane & 3) * 8;
    const u16* gA = &A   [(size_t)(row0 + w * 16 + crow) * K + ck];
    const u16* gB = &Wall[(size_t)(col0 + w * 16 + crow) * K + ck];
    const int lo = w * 512;

    gld16(gA, &Asm[0][lo]);
    gld16(gB, &Bsm[0][lo]);
    __syncthreads();

    const int nT = K / GBK;
    for (int t = 0; t < nT; ++t) {
        const int buf = t & 1;
        if (t + 1 < nT) {
            const int k0 = (t + 1) * GBK;
            gld16(gA + k0, &Asm[buf ^ 1][lo]);
            gld16(gB + k0, &Bsm[buf ^ 1][lo]);
        }
        bf16x8 af[2], bf[4];
#pragma unroll
        for (int i = 0; i < 2; ++i)
            af[i] = *(const bf16x8*)&Asm[buf][(rh + i * 16 + l15) * 32 + quad * 8];
#pragma unroll
        for (int j = 0; j < 4; ++j)
            bf[j] = *(const bf16x8*)&Bsm[buf][(cg + j * 16 + l15) * 32 + quad * 8];
#pragma unroll
        for (int i = 0; i < 2; ++i)
#pragma unroll
            for (int j = 0; j < 4; ++j)
                acc[i][j] = mfma16(af[i], bf[j], acc[i][j]);
        if (t + 1 < nT) __syncthreads();
    }

#pragma unroll
    for (int j = 0; j < 4; ++j) {
        const int col = col0 + cg + j * 16 + l15;
        if (col < 512) {
#pragma unroll
            for (int i = 0; i < 2; ++i)
#pragma unroll
                for (int r = 0; r < 4; ++r)
                    xtb[(size_t)(row0 + rh + i * 16 + quad * 4 + r) * 512 + col] =
                        f2bf(acc[i][j][r]);
        } else if (col < 1536) {
            const float bc = (col < 1024) ? bq[col - 512] : bk[col - 1024];
            const float scale = (col < 1024) ? QSCALE : 1.0f;
#pragma unroll
            for (int i = 0; i < 2; ++i)
#pragma unroll
                for (int r = 0; r < 4; ++r)
                    qkvb[(size_t)(row0 + rh + i * 16 + quad * 4 + r) * QKVLD + col - 512] =
                        f2bf((acc[i][j][r] + bc) * scale);
        } else {
            const int hd = col - 1536;
            const float bc = bv[hd];
#pragma unroll
            for (int i = 0; i < 2; ++i) {
                ushort4 pk;
                pk.x = f2bf(acc[i][j][0] + bc);
                pk.y = f2bf(acc[i][j][1] + bc);
                pk.z = f2bf(acc[i][j][2] + bc);
                pk.w = f2bf(acc[i][j][3] + bc);
                *(uint2*)&vtb[(size_t)hd * N_NODES + row0 + rh + i * 16 + quad * 4] =
                    *(uint2*)&pk;
            }
        }
    }
}

// ---------------------------------------------------------------------------
// Fused prep (one launch, 7952 blocks)
// ---------------------------------------------------------------------------
__device__ inline float block_sum_256(float v, float* red4) {
#pragma unroll
    for (int o = 32; o > 0; o >>= 1) v += __shfl_down(v, o, 64);
    const int lane = threadIdx.x & 63;
    const int w = threadIdx.x >> 6;
    if (lane == 0) red4[w] = v;
    __syncthreads();
    return red4[0] + red4[1] + red4[2] + red4[3];
}

__launch_bounds__(256)
__global__ void prep_kernel(
    const float* __restrict__ Wg, const float* __restrict__ Wq,
    const float* __restrict__ Wk, const float* __restrict__ Wv,
    const float* __restrict__ Wo, const float* __restrict__ W1,
    const float* __restrict__ W2, const float* __restrict__ Wa,
    u16* __restrict__ Wgt, u16* __restrict__ Wqt, u16* __restrict__ Wkt,
    u16* __restrict__ Wvt, u16* __restrict__ Wot, u16* __restrict__ W1t,
    u16* __restrict__ W2t, u16* __restrict__ Wat,
    const float* __restrict__ x, u16* __restrict__ xb,
    const float* __restrict__ ln1s, const float* __restrict__ ln1b,
    u16* __restrict__ hb, float* __restrict__ deg, int* __restrict__ cnt) {
    __shared__ u16 t[32][34];
    __shared__ float redA[4];
    __shared__ float redB[4];
    const int id = blockIdx.x;

    if (id < 3840) {
        const float* W; u16* Wt; int K, Nn, bx, by;
        if (id < 1280) {
            const int m = id >> 8, tt = id & 255;
            bx = tt & 15; by = tt >> 4; K = 512; Nn = 512;
            W  = (m == 0) ? Wg  : (m == 1) ? Wq  : (m == 2) ? Wk  : (m == 3) ? Wv  : Wo;
            Wt = (m == 0) ? Wgt : (m == 1) ? Wqt : (m == 2) ? Wkt : (m == 3) ? Wvt : Wot;
        } else if (id < 2304) {
            const int tt = id - 1280; bx = tt & 63; by = tt >> 6;
            K = 512; Nn = 2048; W = W1; Wt = W1t;
        } else if (id < 3328) {
            const int tt = id - 2304; bx = tt & 15; by = tt >> 4;
            K = 2048; Nn = 512; W = W2; Wt = W2t;
        } else {
            const int tt = id - 3328; bx = tt & 15; by = tt >> 4;
            K = 1024; Nn = 512; W = Wa; Wt = Wat;
        }
        const int k0 = by * 32, n0 = bx * 32;
        const int r = threadIdx.x >> 3, c4 = (threadIdx.x & 7) * 4;
        float4 v = *(const float4*)&W[(size_t)(k0 + r) * Nn + n0 + c4];
        t[r][c4 + 0] = f2bf(v.x); t[r][c4 + 1] = f2bf(v.y);
        t[r][c4 + 2] = f2bf(v.z); t[r][c4 + 3] = f2bf(v.w);
        __syncthreads();
        u16 tmp[4];
#pragma unroll
        for (int i = 0; i < 4; ++i) tmp[i] = t[c4 + i][r];
        u16* op = Wt + (size_t)(n0 + r) * K + k0 + c4;
        *(uint2*)op = *(uint2*)tmp;
    } else if (id < 7936) {
        const int row = id - 3840;
        const int tid = threadIdx.x;
        const float* xr = x + (size_t)row * DMODEL;
        float v0 = xr[tid], v1 = xr[tid + 256];
        xb[(size_t)row * DMODEL + tid] = f2bf(v0);
        xb[(size_t)row * DMODEL + tid + 256] = f2bf(v1);
        float total = block_sum_256(v0 + v1, redA);
        float mean = total * (1.0f / DMODEL);
        float d0 = v0 - mean, d1 = v1 - mean;
        float sq = block_sum_256(d0 * d0 + d1 * d1, redB);
        float inv = rsqrtf(sq * (1.0f / DMODEL) + 1e-5f);
        hb[(size_t)row * DMODEL + tid] = f2bf(d0 * inv * ln1s[tid] + ln1b[tid]);
        hb[(size_t)row * DMODEL + tid + 256] =
            f2bf(d1 * inv * ln1s[tid + 256] + ln1b[tid + 256]);
    } else {
        int i = (id - 7936) * 256 + threadIdx.x;
        deg[i] = 1.0f;
        cnt[i] = 0;
    }
}

// ---------------------------------------------------------------------------
// LayerNorm (standalone, for ln2)
// ---------------------------------------------------------------------------
__launch_bounds__(256)
__global__ void ln_kernel(const float* __restrict__ X, const float* __restrict__ s,
                          const float* __restrict__ b, u16* __restrict__ Y) {
    __shared__ float redA[4];
    __shared__ float redB[4];
    const int row = blockIdx.x;
    const int tid = threadIdx.x;
    const float* xr = X + (size_t)row * DMODEL;
    float v0 = xr[tid], v1 = xr[tid + 256];
    float total = block_sum_256(v0 + v1, redA);
    float mean = total * (1.0f / DMODEL);
    float d0 = v0 - mean, d1 = v1 - mean;
    float sq = block_sum_256(d0 * d0 + d1 * d1, redB);
    float inv = rsqrtf(sq * (1.0f / DMODEL) + 1e-5f);
    Y[(size_t)row * DMODEL + tid] = f2bf(d0 * inv * s[tid] + b[tid]);
    Y[(size_t)row * DMODEL + tid + 256] = f2bf(d1 * inv * s[tid + 256] + b[tid + 256]);
}

// ---------------------------------------------------------------------------
// GCN: CSR build + gather
// ---------------------------------------------------------------------------
__global__ void gcn_count_kernel(const int* __restrict__ ei, const float* __restrict__ ew,
                                 float* __restrict__ deg, int* __restrict__ cnt) {
    int e = blockIdx.x * 256 + threadIdx.x;
    int d = ei[NEDGE + e];
    atomicAdd(&cnt[d], 1);
    atomicAdd(&deg[d], ew[e]);
}

__launch_bounds__(256)
__global__ void gcn_prefix_kernel(const int* __restrict__ cnt, int* __restrict__ off,
                                  int* __restrict__ cur, const float* __restrict__ deg,
                                  float* __restrict__ dinv) {
    __shared__ int part[256];
    const int tid = threadIdx.x;
    int local[16];
    int s = 0;
#pragma unroll
    for (int i = 0; i < 16; ++i) { local[i] = s; s += cnt[tid * 16 + i]; }
    part[tid] = s;
#pragma unroll
    for (int i = 0; i < 16; ++i) {
        const int n = tid * 16 + i;
        float d = deg[n];
        dinv[n] = (d > 0.f) ? rsqrtf(fmaxf(d, 1e-12f)) : 0.f;
    }
    __syncthreads();
    if (tid == 0) {
        int run = 0;
        for (int j = 0; j < 256; ++j) { int t = part[j]; part[j] = run; run += t; }
        off[N_NODES] = run;
    }
    __syncthreads();
    int p = part[tid];
#pragma unroll
    for (int i = 0; i < 16; ++i) {
        off[tid * 16 + i] = p + local[i];
        cur[tid * 16 + i] = p + local[i];
    }
}

__global__ void gcn_fill_kernel(const int* __restrict__ ei, const float* __restrict__ ew,
                                int* __restrict__ cur, int* __restrict__ esrc,
                                float* __restrict__ eww) {
    int e = blockIdx.x * 256 + threadIdx.x;
    int s = ei[e], d = ei[NEDGE + e];
    int pos = atomicAdd(&cur[d], 1);
    esrc[pos] = s;
    eww[pos] = ew[e];
}

__launch_bounds__(256)
__global__ void gcn_gather_kernel(const u16* __restrict__ xtb, const int* __restrict__ off,
                                  const int* __restrict__ esrc, const float* __restrict__ eww,
                                  const float* __restrict__ dinv, const float* __restrict__ bg,
                                  u16* __restrict__ catb) {
    const int d = blockIdx.x;
    const int b0 = off[d], b1 = off[d + 1];
    const float did = dinv[d];
    const int c = threadIdx.x * 2;
    float a0 = 0.f, a1 = 0.f;
    for (int j = b0; j < b1; ++j) {
        const int s = esrc[j];
        const float coef = dinv[s] * eww[j] * did;
        const unsigned pv = *(const unsigned*)&xtb[(size_t)s * DMODEL + c];
        a0 += coef * bf2f((u16)(pv & 0xffff));
        a1 += coef * bf2f((u16)(pv >> 16));
    }
    {
        const unsigned pv = *(const unsigned*)&xtb[(size_t)d * DMODEL + c];
        const float sl = did * did;
        a0 += sl * bf2f((u16)(pv & 0xffff));
        a1 += sl * bf2f((u16)(pv >> 16));
    }
    const unsigned pk = (unsigned)f2bf(a0 + bg[c]) | ((unsigned)f2bf(a1 + bg[c + 1]) << 16);
    *(unsigned*)&catb[(size_t)d * 1024 + c] = pk;
}

// ---------------------------------------------------------------------------
// MFMA flash attention. TQ=256 rows/block (64/wave, a=0..3), K-SPLIT x4.
// Double-buffered K/V (load-early/write-late), register-cached K/V frags.
// No setprio (R9: removing it freed cross-a interleave, 53.7 -> 51.9 us).
// ---------------------------------------------------------------------------
#define TK 64
#define AP 72
#define NSPLIT 4
#define KSPAN (N_NODES / NSPLIT)
#define TQ 256

__launch_bounds__(256, 2)
__global__ void attn_kernel(const u16* __restrict__ Qkv, const u16* __restrict__ Vtb,
                            u16* __restrict__ Ob0, u16* __restrict__ Ob1,
                            float* __restrict__ lpart) {
    __shared__ u16 Ks[2][64 * AP];
    __shared__ u16 Vs[2][64 * AP];

    const int h = blockIdx.x;
    const int q0 = blockIdx.y * TQ;
    const int sp = blockIdx.z;
    u16* __restrict__ Opx = ((sp < 2) ? Ob0 : Ob1) + (size_t)(sp & 1) * N_NODES * DMODEL;
    const int kbase = sp * KSPAN;

    const int tid = threadIdx.x;
    const int w = tid >> 6;
    const int lane = tid & 63;
    const int quad = lane >> 4;
    const int l15 = lane & 15;

    // Q fragments: 4 a-blocks of 16 rows each (wave rows q0 + w*64 .. +63)
    const u16* qp = Qkv + (size_t)(q0 + w * 64 + l15) * QKVLD + h * DHEAD + quad * 8;
    bf16x8 qf[4][2];
#pragma unroll
    for (int a = 0; a < 4; ++a) {
        qf[a][0] = *(const bf16x8*)(qp + (size_t)a * 16 * QKVLD);
        qf[a][1] = *(const bf16x8*)(qp + (size_t)a * 16 * QKVLD + 32);
    }

    f32x4 Oa[4][4];
#pragma unroll
    for (int a = 0; a < 4; ++a)
#pragma unroll
        for (int g = 0; g < 4; ++g) Oa[a][g] = (f32x4){0.f, 0.f, 0.f, 0.f};
    float ls[4] = {0.f, 0.f, 0.f, 0.f};

    const int srow = (tid & 127) >> 1;
    const int scol = (tid & 1) * 32;
    const bool isK = (tid < 128);

    // prologue: stage tile 0 into buffer 0
    {
        if (isK) {
            const uint4* kg = (const uint4*)(Qkv + (size_t)(kbase + srow) * QKVLD + 512 + h * DHEAD + scol);
            uint4* kd = (uint4*)&Ks[0][srow * AP + scol];
            kd[0] = kg[0]; kd[1] = kg[1]; kd[2] = kg[2]; kd[3] = kg[3];
        } else {
            const uint4* vg = (const uint4*)(Vtb + ((size_t)h * DHEAD + srow) * N_NODES + kbase + scol);
            uint4* vd = (uint4*)&Vs[0][srow * AP + scol];
            vd[0] = vg[0]; vd[1] = vg[1]; vd[2] = vg[2]; vd[3] = vg[3];
        }
    }
    __syncthreads();

    const int NT = KSPAN / TK;   // 16
    for (int t = 0; t < NT; ++t) {
        const int buf = t & 1;
        const bool more = (t + 1 < NT);
        uint4 s0, s1, s2, s3;
        if (more) {
            // issue next-tile global loads EARLY; latency hides under compute
            const int kn = kbase + (t + 1) * TK;
            if (isK) {
                const uint4* kg = (const uint4*)(Qkv + (size_t)(kn + srow) * QKVLD + 512 + h * DHEAD + scol);
                s0 = kg[0]; s1 = kg[1]; s2 = kg[2]; s3 = kg[3];
            } else {
                const uint4* vg = (const uint4*)(Vtb + ((size_t)h * DHEAD + srow) * N_NODES + kn + scol);
                s0 = vg[0]; s1 = vg[1]; s2 = vg[2]; s3 = vg[3];
            }
        }

        // LDS -> register fragments (reused across all 4 a-blocks)
        bf16x8 kf0[4], kf1[4];
#pragma unroll
        for (int f = 0; f < 4; ++f) {
            const u16* kr = &Ks[buf][(f * 16 + l15) * AP + quad * 8];
            kf0[f] = *(const bf16x8*)kr;
            kf1[f] = *(const bf16x8*)(kr + 32);
        }
        s16x4 vv[4][4];
#pragma unroll
        for (int g = 0; g < 4; ++g)
#pragma unroll
            for (int f = 0; f < 4; ++f)
                vv[f][g] = *(const s16x4*)&Vs[buf][(g * 16 + l15) * AP + f * 16 + quad * 4];

#pragma unroll
        for (int a = 0; a < 4; ++a) {
            f32x4 St[4];
#pragma unroll
            for (int f = 0; f < 4; ++f) {
                f32x4 z = (f32x4){0.f, 0.f, 0.f, 0.f};
                z = mfma16(kf0[f], qf[a][0], z);
                St[f] = mfma16(kf1[f], qf[a][1], z);
            }
            s16x4 pk[4];
#pragma unroll
            for (int f = 0; f < 4; ++f) {
                f32x4 p;
                p[0] = fast_exp2(St[f][0]);
                p[1] = fast_exp2(St[f][1]);
                p[2] = fast_exp2(St[f][2]);
                p[3] = fast_exp2(St[f][3]);
                ls[a] += (p[0] + p[1]) + (p[2] + p[3]);
                pk[f] = pack_bf4(p);
            }
#pragma unroll
            for (int f = 0; f < 4; ++f)
#pragma unroll
                for (int g = 0; g < 4; ++g)
                    Oa[a][g] = mfma1k(pk[f], vv[f][g], Oa[a][g]);
        }

        if (more) {
            // write-late: lands in the other buffer after compute on this one
            if (isK) {
                uint4* kd = (uint4*)&Ks[buf ^ 1][srow * AP + scol];
                kd[0] = s0; kd[1] = s1; kd[2] = s2; kd[3] = s3;
            } else {
                uint4* vd = (uint4*)&Vs[buf ^ 1][srow * AP + scol];
                vd[0] = s0; vd[1] = s1; vd[2] = s2; vd[3] = s3;
            }
            __syncthreads();
        }
    }

#pragma unroll
    for (int a = 0; a < 4; ++a) {
        float s = ls[a];
        s += __shfl_xor(s, 16, 64);
        s += __shfl_xor(s, 32, 64);
        const int rowbase = q0 + w * 64 + a * 16;
        if (quad == 0)
            lpart[(size_t)(rowbase + l15) * 32 + sp * 8 + h] = s;
#pragma unroll
        for (int r = 0; r < 4; ++r) {
            u16* op = Opx + (size_t)(rowbase + quad * 4 + r) * DMODEL + h * DHEAD + l15;
#pragma unroll
            for (int g = 0; g < 4; ++g) op[g * 16] = f2bf(Oa[a][g][r]);
        }
    }
}

// ---------------------------------------------------------------------------
// host side
// ---------------------------------------------------------------------------
static void mgemm64(hipStream_t st, const u16* A, const u16* Bt, const float* bias,
                    const float* res, void* C, int M, int Nn, int K, float scale,
                    int act, int obf16, int ldC, int ldRes) {
    dim3 g(Nn / GBN, M / 64), b(512);
    if (act)
        hipLaunchKernelGGL((mfma_gemm64<1, 1>), g, b, 0, st, A, Bt, bias, res, C, M, Nn, K, scale, ldC, ldRes);
    else if (obf16)
        hipLaunchKernelGGL((mfma_gemm64<0, 1>), g, b, 0, st, A, Bt, bias, res, C, M, Nn, K, scale, ldC, ldRes);
    else
        hipLaunchKernelGGL((mfma_gemm64<0, 0>), g, b, 0, st, A, Bt, bias, res, C, M, Nn, K, scale, ldC, ldRes);
}

extern "C" void kernel_launch(void* const* d_in, const int* in_sizes, int n_in,
                              void* d_out, int out_size, void* d_ws, size_t ws_size,
                              hipStream_t stream) {
    const float* x    = (const float*)d_in[0];
    const int*   ei   = (const int*)d_in[1];
    const float* ew   = (const float*)d_in[2];
    const float* Wg   = (const float*)d_in[3];
    const float* bg   = (const float*)d_in[4];
    const float* ln1s = (const float*)d_in[5];
    const float* ln1b = (const float*)d_in[6];
    const float* Wq   = (const float*)d_in[7];
    const float* bq   = (const float*)d_in[8];
    const float* Wk   = (const float*)d_in[9];
    const float* bk   = (const float*)d_in[10];
    const float* Wv   = (const float*)d_in[11];
    const float* bv   = (const float*)d_in[12];
    const float* Wo   = (const float*)d_in[13];
    const float* bo   = (const float*)d_in[14];
    const float* ln2s = (const float*)d_in[15];
    const float* ln2b = (const float*)d_in[16];
    const float* W1   = (const float*)d_in[17];
    const float* b1   = (const float*)d_in[18];
    const float* W2   = (const float*)d_in[19];
    const float* b2   = (const float*)d_in[20];
    const float* Wa   = (const float*)d_in[21];
    const float* ba   = (const float*)d_in[22];
    float* out = (float*)d_out;
    float* ws  = (float*)d_ws;

    const size_t SLOT = (size_t)N_NODES * DMODEL;  // 2M floats = 8 MB

    u16* xtb = (u16*)ws;
    u16* Ob0 = (u16*)ws;               // splits 0,1 (after gather consumes xtb)
    float* lpart = ws + SLOT;          // [4096][32] fp32 = 512 KB
    int*   esrc  = (int*)(ws + SLOT + 327680);
    float* eww   = (float*)(esrc + NEDGE);
    int*   off   = (int*)(eww + NEDGE);
    int*   cur   = off + 4100;
    int*   cnt   = cur + 4096;
    u16* Ob1 = (u16*)(ws + 2 * SLOT);  // splits 2,3
    u16* hb  = (u16*)(ws + 3 * SLOT);
    u16* h2b = hb + SLOT;
    u16*   qkvb = (u16*)(ws + 4 * SLOT);
    float* x1   = ws + 4 * SLOT;
    u16*   vtb  = (u16*)(ws + 5 * SLOT) + SLOT;
    u16* midb = (u16*)(ws + 6 * SLOT);
    u16* catb = (u16*)(ws + 8 * SLOT);
    u16* xb   = catb;
    u16* Wgt = (u16*)(ws + 9 * SLOT);
    u16* Wqt = Wgt + 262144;
    u16* Wkt = Wqt + 262144;
    u16* Wvt = Wkt + 262144;
    u16* Wot = Wvt + 262144;
    u16* W1t = Wot + 262144;
    u16* W2t = W1t + 1048576;
    u16* Wat = W2t + 1048576;
    float* deg  = (float*)(Wat + 524288);
    float* dinv = deg + N_NODES;

    hipLaunchKernelGGL(prep_kernel, dim3(7952), dim3(256), 0, stream,
                       Wg, Wq, Wk, Wv, Wo, W1, W2, Wa,
                       Wgt, Wqt, Wkt, Wvt, Wot, W1t, W2t, Wat,
                       x, xb, ln1s, ln1b, hb, deg, cnt);

    hipLaunchKernelGGL(qkvg_gemm, dim3(16, 32), dim3(512), 0, stream,
                       xb, hb, Wgt, bq, bk, bv, xtb, qkvb, vtb);

    hipLaunchKernelGGL(gcn_count_kernel, dim3(NEDGE / 256), dim3(256), 0, stream, ei, ew, deg, cnt);
    hipLaunchKernelGGL(gcn_prefix_kernel, dim3(1), dim3(256), 0, stream, cnt, off, cur, deg, dinv);
    hipLaunchKernelGGL(gcn_fill_kernel, dim3(NEDGE / 256), dim3(256), 0, stream, ei, ew, cur, esrc, eww);
    hipLaunchKernelGGL(gcn_gather_kernel, dim3(N_NODES), dim3(256), 0, stream,
                       xtb, off, esrc, eww, dinv, bg, catb);

    hipLaunchKernelGGL(attn_kernel, dim3(NHEAD, N_NODES / TQ, NSPLIT), dim3(256), 0, stream,
                       qkvb, vtb, Ob0, Ob1, lpart);

    hipLaunchKernelGGL(wo_gemm, dim3(4, 64), dim3(512), 0, stream,
                       Ob0, Ob1, lpart, Wot, bo, x, x1);

    hipLaunchKernelGGL(ln_kernel, dim3(N_NODES), dim3(256), 0, stream, x1, ln2s, ln2b, h2b);
    // W1: 128x128-tile high-intensity GEMM (grid 16x32 = 512 blocks)
    hipLaunchKernelGGL((mfma_gemm128<1, 1>), dim3(DFF / 128, N_NODES / 128), dim3(512), 0, stream,
                       h2b, W1t, b1, nullptr, midb, N_NODES, DFF, DMODEL, 1.0f, DFF, DFF);
    mgemm64(stream, midb, W2t, b2, x1, catb + 512, N_NODES, DMODEL, DFF, 1.0f, 0, 1, 1024, DMODEL);

    mgemm64(stream, catb, Wat, ba, x, out, N_NODES, DMODEL, 2 * DMODEL, 1.0f, 0, 0, DMODEL, DMODEL);
}

// Round 13
// 309.024 us; speedup vs baseline: 1.2792x; 1.0073x over previous
//
#include <hip/hip_runtime.h>
#include <math.h>

#define N_NODES 4096
#define DMODEL  512
#define NHEAD   8
#define DHEAD   64
#define DFF     2048
#define NEDGE   65536
#define QKVLD   1536

typedef unsigned short u16;
typedef __bf16 bf16x8 __attribute__((ext_vector_type(8)));
typedef float  f32x4  __attribute__((ext_vector_type(4)));
typedef short  s16x4  __attribute__((ext_vector_type(4)));

#if defined(__has_builtin)
#if __has_builtin(__builtin_amdgcn_mfma_f32_16x16x16bf16_1k)
#define HAS_MFMA_1K 1
#endif
#if __has_builtin(__builtin_amdgcn_global_load_lds)
#define HAS_GLOAD_LDS 1
#endif
#endif

__device__ inline float fast_exp2(float x) {
    return __builtin_amdgcn_exp2f(x);   // v_exp_f32: 2^x native
}

__device__ inline f32x4 mfma16(bf16x8 a, bf16x8 b, f32x4 c) {
    return __builtin_amdgcn_mfma_f32_16x16x32_bf16(a, b, c, 0, 0, 0);
}

__device__ inline u16 f2bf(float f) {  // RNE
    union { float f; unsigned u; } v; v.f = f;
    unsigned r = v.u + 0x7fff + ((v.u >> 16) & 1);
    return (u16)(r >> 16);
}

#ifdef HAS_MFMA_1K
__device__ inline f32x4 mfma1k(s16x4 a, s16x4 b, f32x4 c) {
    return __builtin_amdgcn_mfma_f32_16x16x16bf16_1k(a, b, c, 0, 0, 0);
}
__device__ inline s16x4 pack_bf4(f32x4 p) {
    union { float f; unsigned u; } a0, a1, a2, a3;
    a0.f = p[0]; a1.f = p[1]; a2.f = p[2]; a3.f = p[3];
    unsigned lo = __builtin_amdgcn_perm(a1.u + 0x8000u, a0.u + 0x8000u, 0x07060302u);
    unsigned hi = __builtin_amdgcn_perm(a3.u + 0x8000u, a2.u + 0x8000u, 0x07060302u);
    union { unsigned u[2]; s16x4 v; } r;
    r.u[0] = lo; r.u[1] = hi;
    return r.v;
}
#else
// Host-pass stubs: gfx950 device pass always defines HAS_MFMA_1K. Parsed, never executed.
__device__ inline f32x4 mfma1k(s16x4 a, s16x4 b, f32x4 c) { return c; }
__device__ inline s16x4 pack_bf4(f32x4 p) {
    union { u16 u[4]; s16x4 v; } r;
    r.u[0] = f2bf(p[0]); r.u[1] = f2bf(p[1]); r.u[2] = f2bf(p[2]); r.u[3] = f2bf(p[3]);
    return r.v;
}
#endif

// async global->LDS, 16B/lane. LDS dest is wave-uniform base + lane*16 (linear!).
__device__ inline void gld16(const u16* g, u16* l) {
#ifdef HAS_GLOAD_LDS
    __builtin_amdgcn_global_load_lds((const __attribute__((address_space(1))) void*)g,
                                     (__attribute__((address_space(3))) void*)l,
                                     16, 0, 0);
#else
    // host-parse stub; device pass on gfx950 always takes the builtin path.
    *(uint4*)l = *(const uint4*)g;
#endif
}

__device__ inline float bf2f(u16 v) {
    union { unsigned u; float f; } t; t.u = ((unsigned)v) << 16; return t.f;
}

__device__ inline float gelu_tanh(float x) {
    float x3 = x * x * x;
    float t = tanhf(0.7978845608028654f * (x + 0.044715f * x3));
    return 0.5f * x * (1.0f + t);
}

#define GBN 128
#define GBK 32
#define GP  40

// ---------------------------------------------------------------------------
// MFMA bf16 GEMM 64x128x32, 512 threads = 8 waves, double-buffered via
// global_load_lds (16B/lane, linear LDS [rows][32]). (W2, Wa)
// ---------------------------------------------------------------------------
template <int ACT, int OBF16>
__launch_bounds__(512)
__global__ void mfma_gemm64(const u16* __restrict__ A, const u16* __restrict__ Bt,
                            const float* __restrict__ bias, const float* __restrict__ res,
                            void* __restrict__ Cout, int M, int Nn, int K, float scale,
                            int ldC, int ldRes) {
    __shared__ u16 Asm[2][64 * 32];
    __shared__ u16 Bsm[2][128 * 32];

    const int tid = threadIdx.x;
    const int w = tid >> 6;
    const int lane = tid & 63;
    const int quad = lane >> 4;
    const int l15 = lane & 15;
    const int row0 = blockIdx.y * 64;
    const int col0 = blockIdx.x * GBN;
    const int rh = (w & 1) * 32;
    const int cg = (w >> 1) * 32;

    f32x4 acc[2][2];
#pragma unroll
    for (int i = 0; i < 2; ++i)
#pragma unroll
        for (int j = 0; j < 2; ++j) acc[i][j] = (f32x4){0.f, 0.f, 0.f, 0.f};

    const int crow = lane >> 2;
    const int ck = (lane & 3) * 8;
    const u16* gB = &Bt[(size_t)(col0 + w * 16 + crow) * K + ck];
    const u16* gA = &A [(size_t)(row0 + (w & 3) * 16 + crow) * K + ck];
    const int lBo = w * 512;
    const int lAo = (w & 3) * 512;

    gld16(gB, &Bsm[0][lBo]);
    if (w < 4) gld16(gA, &Asm[0][lAo]);
    __syncthreads();

    const int nT = K / GBK;
    for (int t = 0; t < nT; ++t) {
        const int buf = t & 1;
        if (t + 1 < nT) {
            const int k0 = (t + 1) * GBK;
            gld16(gB + k0, &Bsm[buf ^ 1][lBo]);
            if (w < 4) gld16(gA + k0, &Asm[buf ^ 1][lAo]);
        }
        bf16x8 af[2], bf[2];
#pragma unroll
        for (int i = 0; i < 2; ++i)
            af[i] = *(const bf16x8*)&Asm[buf][(rh + i * 16 + l15) * 32 + quad * 8];
#pragma unroll
        for (int j = 0; j < 2; ++j)
            bf[j] = *(const bf16x8*)&Bsm[buf][(cg + j * 16 + l15) * 32 + quad * 8];
#pragma unroll
        for (int i = 0; i < 2; ++i)
#pragma unroll
            for (int j = 0; j < 2; ++j)
                acc[i][j] = mfma16(af[i], bf[j], acc[i][j]);
        if (t + 1 < nT) __syncthreads();
    }

#pragma unroll
    for (int j = 0; j < 2; ++j) {
        const int col = col0 + cg + j * 16 + l15;
        const float bc = bias ? bias[col] : 0.f;
#pragma unroll
        for (int i = 0; i < 2; ++i) {
#pragma unroll
            for (int r = 0; r < 4; ++r) {
                const int row = row0 + rh + i * 16 + quad * 4 + r;
                float o = (acc[i][j][r] + bc) * scale;
                if (ACT == 1) o = gelu_tanh(o);
                if (res) o += res[(size_t)row * ldRes + col];
                if (OBF16)
                    ((u16*)Cout)[(size_t)row * ldC + col] = f2bf(o);
                else
                    ((float*)Cout)[(size_t)row * ldC + col] = o;
            }
        }
    }
}

// ---------------------------------------------------------------------------
// MFMA bf16 GEMM 128x128x32, 512 threads = 8 waves, acc[2][4] per wave,
// gload_lds staging, double-buffered. (W1)
// ---------------------------------------------------------------------------
template <int ACT, int OBF16>
__launch_bounds__(512)
__global__ void mfma_gemm128(const u16* __restrict__ A, const u16* __restrict__ Bt,
                             const float* __restrict__ bias, const float* __restrict__ res,
                             void* __restrict__ Cout, int M, int Nn, int K, float scale,
                             int ldC, int ldRes) {
    __shared__ u16 Asm[2][128 * 32];
    __shared__ u16 Bsm[2][128 * 32];

    const int tid = threadIdx.x;
    const int w = tid >> 6;
    const int lane = tid & 63;
    const int quad = lane >> 4;
    const int l15 = lane & 15;
    const int row0 = blockIdx.y * 128;
    const int col0 = blockIdx.x * 128;
    const int rh = (w & 3) * 32;
    const int cg = (w >> 2) * 64;

    f32x4 acc[2][4];
#pragma unroll
    for (int i = 0; i < 2; ++i)
#pragma unroll
        for (int j = 0; j < 4; ++j) acc[i][j] = (f32x4){0.f, 0.f, 0.f, 0.f};

    const int crow = lane >> 2;
    const int ck = (lane & 3) * 8;
    const u16* gA = &A [(size_t)(row0 + w * 16 + crow) * K + ck];
    const u16* gB = &Bt[(size_t)(col0 + w * 16 + crow) * K + ck];
    const int lo = w * 512;

    gld16(gA, &Asm[0][lo]);
    gld16(gB, &Bsm[0][lo]);
    __syncthreads();

    const int nT = K / GBK;
    for (int t = 0; t < nT; ++t) {
        const int buf = t & 1;
        if (t + 1 < nT) {
            const int k0 = (t + 1) * GBK;
            gld16(gA + k0, &Asm[buf ^ 1][lo]);
            gld16(gB + k0, &Bsm[buf ^ 1][lo]);
        }
        bf16x8 af[2], bf[4];
#pragma unroll
        for (int i = 0; i < 2; ++i)
            af[i] = *(const bf16x8*)&Asm[buf][(rh + i * 16 + l15) * 32 + quad * 8];
#pragma unroll
        for (int j = 0; j < 4; ++j)
            bf[j] = *(const bf16x8*)&Bsm[buf][(cg + j * 16 + l15) * 32 + quad * 8];
#pragma unroll
        for (int i = 0; i < 2; ++i)
#pragma unroll
            for (int j = 0; j < 4; ++j)
                acc[i][j] = mfma16(af[i], bf[j], acc[i][j]);
        if (t + 1 < nT) __syncthreads();
    }

#pragma unroll
    for (int j = 0; j < 4; ++j) {
        const int col = col0 + cg + j * 16 + l15;
        const float bc = bias ? bias[col] : 0.f;
#pragma unroll
        for (int i = 0; i < 2; ++i) {
#pragma unroll
            for (int r = 0; r < 4; ++r) {
                const int row = row0 + rh + i * 16 + quad * 4 + r;
                float o = (acc[i][j][r] + bc) * scale;
                if (ACT == 1) o = gelu_tanh(o);
                if (res) o += res[(size_t)row * ldRes + col];
                if (OBF16)
                    ((u16*)Cout)[(size_t)row * ldC + col] = f2bf(o);
                else
                    ((float*)Cout)[(size_t)row * ldC + col] = o;
            }
        }
    }
}

// ---------------------------------------------------------------------------
// Fused Wo GEMM with on-the-fly attention split-reduce in the A path.
// NSPLIT=4: slices in Ob0 (sp 0,1) and Ob1 (sp 2,3). 512 thr.
// B via global_load_lds (linear [128][32]); A computed -> reg-staged (GP=40).
// ---------------------------------------------------------------------------
__device__ inline uint4 reduce4_norm(const u16* b0, const u16* b1, size_t off, float linv) {
    const size_t OFF = (size_t)N_NODES * DMODEL;
    float s[8] = {0.f, 0.f, 0.f, 0.f, 0.f, 0.f, 0.f, 0.f};
    const u16* bs[2] = {b0, b1};
#pragma unroll
    for (int b = 0; b < 2; ++b)
#pragma unroll
        for (int k = 0; k < 2; ++k) {
            uint4 v = *(const uint4*)(bs[b] + k * OFF + off);
            unsigned uu[4] = {v.x, v.y, v.z, v.w};
#pragma unroll
            for (int t = 0; t < 4; ++t) {
                s[2 * t]     += bf2f((u16)(uu[t] & 0xffff));
                s[2 * t + 1] += bf2f((u16)(uu[t] >> 16));
            }
        }
    uint4 r;
    r.x = (unsigned)f2bf(s[0] * linv) | ((unsigned)f2bf(s[1] * linv) << 16);
    r.y = (unsigned)f2bf(s[2] * linv) | ((unsigned)f2bf(s[3] * linv) << 16);
    r.z = (unsigned)f2bf(s[4] * linv) | ((unsigned)f2bf(s[5] * linv) << 16);
    r.w = (unsigned)f2bf(s[6] * linv) | ((unsigned)f2bf(s[7] * linv) << 16);
    return r;
}

__launch_bounds__(512)
__global__ void wo_gemm(const u16* __restrict__ Ob0, const u16* __restrict__ Ob1,
                        const float* __restrict__ lpart, const u16* __restrict__ Bt,
                        const float* __restrict__ bias, const float* __restrict__ res,
                        float* __restrict__ Cout) {
    __shared__ u16 Asm[2][64 * GP];
    __shared__ u16 Bsm[2][128 * 32];

    const int tid = threadIdx.x;
    const int w = tid >> 6;
    const int lane = tid & 63;
    const int quad = lane >> 4;
    const int l15 = lane & 15;
    const int row0 = blockIdx.y * 64;
    const int col0 = blockIdx.x * GBN;
    const int rh = (w & 1) * 32;
    const int cg = (w >> 1) * 32;
    const int K = DMODEL;

    f32x4 acc[2][2];
#pragma unroll
    for (int i = 0; i < 2; ++i)
#pragma unroll
        for (int j = 0; j < 2; ++j) acc[i][j] = (f32x4){0.f, 0.f, 0.f, 0.f};

    // B staging via gload_lds
    const int crow = lane >> 2;
    const int ck = (lane & 3) * 8;
    const u16* gB = &Bt[(size_t)(col0 + w * 16 + crow) * K + ck];
    const int lBo = w * 512;

    // A staging (computed): tid<256, reg path
    const int arow = (tid & 255) >> 2, ak = (tid & 3) * 8;
    const bool doA = (tid < 256);

    float linv[8];
    if (doA) {
        // lpart row: 32 floats, layout [sp*8+h], sp=0..3
        const float* lr = lpart + (size_t)(row0 + arow) * 32;
        float ls[8] = {0.f, 0.f, 0.f, 0.f, 0.f, 0.f, 0.f, 0.f};
#pragma unroll
        for (int v = 0; v < 8; ++v) {
            float4 q = *(const float4*)&lr[v * 4];
            ls[(v * 4 + 0) & 7] += q.x;
            ls[(v * 4 + 1) & 7] += q.y;
            ls[(v * 4 + 2) & 7] += q.z;
            ls[(v * 4 + 3) & 7] += q.w;
        }
#pragma unroll
        for (int hh = 0; hh < 8; ++hh) linv[hh] = 1.0f / ls[hh];
    }

    {
        gld16(gB, &Bsm[0][lBo]);
        if (doA) {
            uint4 a0 = reduce4_norm(Ob0, Ob1, (size_t)(row0 + arow) * DMODEL + ak, linv[0]);
            *(uint4*)&Asm[0][arow * GP + ak] = a0;
        }
    }
    __syncthreads();

#pragma unroll
    for (int t = 0; t < 16; ++t) {
        const int buf = t & 1;
        uint4 an;
        if (t + 1 < 16) {
            const int k0 = (t + 1) * GBK;
            gld16(gB + k0, &Bsm[buf ^ 1][lBo]);
            if (doA)
                an = reduce4_norm(Ob0, Ob1, (size_t)(row0 + arow) * DMODEL + k0 + ak,
                                  linv[(t + 1) >> 1]);
        }
        bf16x8 af[2], bf[2];
#pragma unroll
        for (int i = 0; i < 2; ++i)
            af[i] = *(const bf16x8*)&Asm[buf][(rh + i * 16 + l15) * GP + quad * 8];
#pragma unroll
        for (int j = 0; j < 2; ++j)
            bf[j] = *(const bf16x8*)&Bsm[buf][(cg + j * 16 + l15) * 32 + quad * 8];
#pragma unroll
        for (int i = 0; i < 2; ++i)
#pragma unroll
            for (int j = 0; j < 2; ++j)
                acc[i][j] = mfma16(af[i], bf[j], acc[i][j]);
        if (t + 1 < 16) {
            if (doA) *(uint4*)&Asm[buf ^ 1][arow * GP + ak] = an;
            __syncthreads();
        }
    }

#pragma unroll
    for (int j = 0; j < 2; ++j) {
        const int col = col0 + cg + j * 16 + l15;
        const float bc = bias[col];
#pragma unroll
        for (int i = 0; i < 2; ++i) {
#pragma unroll
            for (int r = 0; r < 4; ++r) {
                const int row = row0 + rh + i * 16 + quad * 4 + r;
                Cout[(size_t)row * DMODEL + col] =
                    acc[i][j][r] + bc + res[(size_t)row * DMODEL + col];
            }
        }
    }
}

// ---------------------------------------------------------------------------
// Batched Wg+Q+K+V GEMM, 128x128 tile, 512 thr, acc[2][4], gload_lds.
// ---------------------------------------------------------------------------
#define QSCALE 0.1803368801111204f   // 0.125 * log2(e)

__launch_bounds__(512)
__global__ void qkvg_gemm(const u16* __restrict__ xb, const u16* __restrict__ hb,
                          const u16* __restrict__ Wall,
                          const float* __restrict__ bq, const float* __restrict__ bk,
                          const float* __restrict__ bv,
                          u16* __restrict__ xtb, u16* __restrict__ qkvb,
                          u16* __restrict__ vtb) {
    __shared__ u16 Asm[2][128 * 32];
    __shared__ u16 Bsm[2][128 * 32];

    const int tid = threadIdx.x;
    const int w = tid >> 6;
    const int lane = tid & 63;
    const int quad = lane >> 4;
    const int l15 = lane & 15;
    const int row0 = blockIdx.y * 128;
    const int col0 = blockIdx.x * 128;
    const int rh = (w & 3) * 32;
    const int cg = (w >> 2) * 64;
    const int K = DMODEL;
    const u16* A = (col0 < 512) ? xb : hb;

    f32x4 acc[2][4];
#pragma unroll
    for (int i = 0; i < 2; ++i)
#pragma unroll
        for (int j = 0; j < 4; ++j) acc[i][j] = (f32x4){0.f, 0.f, 0.f, 0.f};

    const int crow = lane >> 2;
    const int ck = (lane & 3) * 8;
    const u16* gA = &A   [(size_t)(row0 + w * 16 + crow) * K + ck];
    const u16* gB = &Wall[(size_t)(col0 + w * 16 + crow) * K + ck];
    const int lo = w * 512;

    gld16(gA, &Asm[0][lo]);
    gld16(gB, &Bsm[0][lo]);
    __syncthreads();

    const int nT = K / GBK;
    for (int t = 0; t < nT; ++t) {
        const int buf = t & 1;
        if (t + 1 < nT) {
            const int k0 = (t + 1) * GBK;
            gld16(gA + k0, &Asm[buf ^ 1][lo]);
            gld16(gB + k0, &Bsm[buf ^ 1][lo]);
        }
        bf16x8 af[2], bf[4];
#pragma unroll
        for (int i = 0; i < 2; ++i)
            af[i] = *(const bf16x8*)&Asm[buf][(rh + i * 16 + l15) * 32 + quad * 8];
#pragma unroll
        for (int j = 0; j < 4; ++j)
            bf[j] = *(const bf16x8*)&Bsm[buf][(cg + j * 16 + l15) * 32 + quad * 8];
#pragma unroll
        for (int i = 0; i < 2; ++i)
#pragma unroll
            for (int j = 0; j < 4; ++j)
                acc[i][j] = mfma16(af[i], bf[j], acc[i][j]);
        if (t + 1 < nT) __syncthreads();
    }

#pragma unroll
    for (int j = 0; j < 4; ++j) {
        const int col = col0 + cg + j * 16 + l15;
        if (col < 512) {
#pragma unroll
            for (int i = 0; i < 2; ++i)
#pragma unroll
                for (int r = 0; r < 4; ++r)
                    xtb[(size_t)(row0 + rh + i * 16 + quad * 4 + r) * 512 + col] =
                        f2bf(acc[i][j][r]);
        } else if (col < 1536) {
            const float bc = (col < 1024) ? bq[col - 512] : bk[col - 1024];
            const float scale = (col < 1024) ? QSCALE : 1.0f;
#pragma unroll
            for (int i = 0; i < 2; ++i)
#pragma unroll
                for (int r = 0; r < 4; ++r)
                    qkvb[(size_t)(row0 + rh + i * 16 + quad * 4 + r) * QKVLD + col - 512] =
                        f2bf((acc[i][j][r] + bc) * scale);
        } else {
            const int hd = col - 1536;
            const float bc = bv[hd];
#pragma unroll
            for (int i = 0; i < 2; ++i) {
                ushort4 pk;
                pk.x = f2bf(acc[i][j][0] + bc);
                pk.y = f2bf(acc[i][j][1] + bc);
                pk.z = f2bf(acc[i][j][2] + bc);
                pk.w = f2bf(acc[i][j][3] + bc);
                *(uint2*)&vtb[(size_t)hd * N_NODES + row0 + rh + i * 16 + quad * 4] =
                    *(uint2*)&pk;
            }
        }
    }
}

// ---------------------------------------------------------------------------
// Fused prep (one launch, 7952 blocks)
// ---------------------------------------------------------------------------
__device__ inline float block_sum_256(float v, float* red4) {
#pragma unroll
    for (int o = 32; o > 0; o >>= 1) v += __shfl_down(v, o, 64);
    const int lane = threadIdx.x & 63;
    const int w = threadIdx.x >> 6;
    if (lane == 0) red4[w] = v;
    __syncthreads();
    return red4[0] + red4[1] + red4[2] + red4[3];
}

__launch_bounds__(256)
__global__ void prep_kernel(
    const float* __restrict__ Wg, const float* __restrict__ Wq,
    const float* __restrict__ Wk, const float* __restrict__ Wv,
    const float* __restrict__ Wo, const float* __restrict__ W1,
    const float* __restrict__ W2, const float* __restrict__ Wa,
    u16* __restrict__ Wgt, u16* __restrict__ Wqt, u16* __restrict__ Wkt,
    u16* __restrict__ Wvt, u16* __restrict__ Wot, u16* __restrict__ W1t,
    u16* __restrict__ W2t, u16* __restrict__ Wat,
    const float* __restrict__ x, u16* __restrict__ xb,
    const float* __restrict__ ln1s, const float* __restrict__ ln1b,
    u16* __restrict__ hb, float* __restrict__ deg, int* __restrict__ cnt) {
    __shared__ u16 t[32][34];
    __shared__ float redA[4];
    __shared__ float redB[4];
    const int id = blockIdx.x;

    if (id < 3840) {
        const float* W; u16* Wt; int K, Nn, bx, by;
        if (id < 1280) {
            const int m = id >> 8, tt = id & 255;
            bx = tt & 15; by = tt >> 4; K = 512; Nn = 512;
            W  = (m == 0) ? Wg  : (m == 1) ? Wq  : (m == 2) ? Wk  : (m == 3) ? Wv  : Wo;
            Wt = (m == 0) ? Wgt : (m == 1) ? Wqt : (m == 2) ? Wkt : (m == 3) ? Wvt : Wot;
        } else if (id < 2304) {
            const int tt = id - 1280; bx = tt & 63; by = tt >> 6;
            K = 512; Nn = 2048; W = W1; Wt = W1t;
        } else if (id < 3328) {
            const int tt = id - 2304; bx = tt & 15; by = tt >> 4;
            K = 2048; Nn = 512; W = W2; Wt = W2t;
        } else {
            const int tt = id - 3328; bx = tt & 15; by = tt >> 4;
            K = 1024; Nn = 512; W = Wa; Wt = Wat;
        }
        const int k0 = by * 32, n0 = bx * 32;
        const int r = threadIdx.x >> 3, c4 = (threadIdx.x & 7) * 4;
        float4 v = *(const float4*)&W[(size_t)(k0 + r) * Nn + n0 + c4];
        t[r][c4 + 0] = f2bf(v.x); t[r][c4 + 1] = f2bf(v.y);
        t[r][c4 + 2] = f2bf(v.z); t[r][c4 + 3] = f2bf(v.w);
        __syncthreads();
        u16 tmp[4];
#pragma unroll
        for (int i = 0; i < 4; ++i) tmp[i] = t[c4 + i][r];
        u16* op = Wt + (size_t)(n0 + r) * K + k0 + c4;
        *(uint2*)op = *(uint2*)tmp;
    } else if (id < 7936) {
        const int row = id - 3840;
        const int tid = threadIdx.x;
        const float* xr = x + (size_t)row * DMODEL;
        float v0 = xr[tid], v1 = xr[tid + 256];
        xb[(size_t)row * DMODEL + tid] = f2bf(v0);
        xb[(size_t)row * DMODEL + tid + 256] = f2bf(v1);
        float total = block_sum_256(v0 + v1, redA);
        float mean = total * (1.0f / DMODEL);
        float d0 = v0 - mean, d1 = v1 - mean;
        float sq = block_sum_256(d0 * d0 + d1 * d1, redB);
        float inv = rsqrtf(sq * (1.0f / DMODEL) + 1e-5f);
        hb[(size_t)row * DMODEL + tid] = f2bf(d0 * inv * ln1s[tid] + ln1b[tid]);
        hb[(size_t)row * DMODEL + tid + 256] =
            f2bf(d1 * inv * ln1s[tid + 256] + ln1b[tid + 256]);
    } else {
        int i = (id - 7936) * 256 + threadIdx.x;
        deg[i] = 1.0f;
        cnt[i] = 0;
    }
}

// ---------------------------------------------------------------------------
// LayerNorm (standalone, for ln2)
// ---------------------------------------------------------------------------
__launch_bounds__(256)
__global__ void ln_kernel(const float* __restrict__ X, const float* __restrict__ s,
                          const float* __restrict__ b, u16* __restrict__ Y) {
    __shared__ float redA[4];
    __shared__ float redB[4];
    const int row = blockIdx.x;
    const int tid = threadIdx.x;
    const float* xr = X + (size_t)row * DMODEL;
    float v0 = xr[tid], v1 = xr[tid + 256];
    float total = block_sum_256(v0 + v1, redA);
    float mean = total * (1.0f / DMODEL);
    float d0 = v0 - mean, d1 = v1 - mean;
    float sq = block_sum_256(d0 * d0 + d1 * d1, redB);
    float inv = rsqrtf(sq * (1.0f / DMODEL) + 1e-5f);
    Y[(size_t)row * DMODEL + tid] = f2bf(d0 * inv * s[tid] + b[tid]);
    Y[(size_t)row * DMODEL + tid + 256] = f2bf(d1 * inv * s[tid + 256] + b[tid + 256]);
}

// ---------------------------------------------------------------------------
// GCN: CSR build + gather
// ---------------------------------------------------------------------------
__global__ void gcn_count_kernel(const int* __restrict__ ei, const float* __restrict__ ew,
                                 float* __restrict__ deg, int* __restrict__ cnt) {
    int e = blockIdx.x * 256 + threadIdx.x;
    int d = ei[NEDGE + e];
    atomicAdd(&cnt[d], 1);
    atomicAdd(&deg[d], ew[e]);
}

__launch_bounds__(256)
__global__ void gcn_prefix_kernel(const int* __restrict__ cnt, int* __restrict__ off,
                                  int* __restrict__ cur, const float* __restrict__ deg,
                                  float* __restrict__ dinv) {
    __shared__ int part[256];
    const int tid = threadIdx.x;
    int local[16];
    int s = 0;
#pragma unroll
    for (int i = 0; i < 16; ++i) { local[i] = s; s += cnt[tid * 16 + i]; }
    part[tid] = s;
#pragma unroll
    for (int i = 0; i < 16; ++i) {
        const int n = tid * 16 + i;
        float d = deg[n];
        dinv[n] = (d > 0.f) ? rsqrtf(fmaxf(d, 1e-12f)) : 0.f;
    }
    __syncthreads();
    if (tid == 0) {
        int run = 0;
        for (int j = 0; j < 256; ++j) { int t = part[j]; part[j] = run; run += t; }
        off[N_NODES] = run;
    }
    __syncthreads();
    int p = part[tid];
#pragma unroll
    for (int i = 0; i < 16; ++i) {
        off[tid * 16 + i] = p + local[i];
        cur[tid * 16 + i] = p + local[i];
    }
}

__global__ void gcn_fill_kernel(const int* __restrict__ ei, const float* __restrict__ ew,
                                int* __restrict__ cur, int* __restrict__ esrc,
                                float* __restrict__ eww) {
    int e = blockIdx.x * 256 + threadIdx.x;
    int s = ei[e], d = ei[NEDGE + e];
    int pos = atomicAdd(&cur[d], 1);
    esrc[pos] = s;
    eww[pos] = ew[e];
}

__launch_bounds__(256)
__global__ void gcn_gather_kernel(const u16* __restrict__ xtb, const int* __restrict__ off,
                                  const int* __restrict__ esrc, const float* __restrict__ eww,
                                  const float* __restrict__ dinv, const float* __restrict__ bg,
                                  u16* __restrict__ catb) {
    const int d = blockIdx.x;
    const int b0 = off[d], b1 = off[d + 1];
    const float did = dinv[d];
    const int c = threadIdx.x * 2;
    float a0 = 0.f, a1 = 0.f;
    for (int j = b0; j < b1; ++j) {
        const int s = esrc[j];
        const float coef = dinv[s] * eww[j] * did;
        const unsigned pv = *(const unsigned*)&xtb[(size_t)s * DMODEL + c];
        a0 += coef * bf2f((u16)(pv & 0xffff));
        a1 += coef * bf2f((u16)(pv >> 16));
    }
    {
        const unsigned pv = *(const unsigned*)&xtb[(size_t)d * DMODEL + c];
        const float sl = did * did;
        a0 += sl * bf2f((u16)(pv & 0xffff));
        a1 += sl * bf2f((u16)(pv >> 16));
    }
    const unsigned pk = (unsigned)f2bf(a0 + bg[c]) | ((unsigned)f2bf(a1 + bg[c + 1]) << 16);
    *(unsigned*)&catb[(size_t)d * 1024 + c] = pk;
}

// ---------------------------------------------------------------------------
// MFMA flash attention. TQ=256 rows/block (64/wave, a=0..3), K-SPLIT x4.
// Double-buffered K/V, register-cached K/V frags, no setprio (R9 win).
// R13: a-loop rotated 1-deep (T15-style): exp/pack(a-1) [VALU] overlaps
// QK(a) [MFMA] in the scheduler's DAG; PV(a-1) follows. Named StP/Stn
// (no runtime indexing -> no scratch).
// ---------------------------------------------------------------------------
#define TK 64
#define AP 72
#define NSPLIT 4
#define KSPAN (N_NODES / NSPLIT)
#define TQ 256

__launch_bounds__(256, 2)
__global__ void attn_kernel(const u16* __restrict__ Qkv, const u16* __restrict__ Vtb,
                            u16* __restrict__ Ob0, u16* __restrict__ Ob1,
                            float* __restrict__ lpart) {
    __shared__ u16 Ks[2][64 * AP];
    __shared__ u16 Vs[2][64 * AP];

    const int h = blockIdx.x;
    const int q0 = blockIdx.y * TQ;
    const int sp = blockIdx.z;
    u16* __restrict__ Opx = ((sp < 2) ? Ob0 : Ob1) + (size_t)(sp & 1) * N_NODES * DMODEL;
    const int kbase = sp * KSPAN;

    const int tid = threadIdx.x;
    const int w = tid >> 6;
    const int lane = tid & 63;
    const int quad = lane >> 4;
    const int l15 = lane & 15;

    // Q fragments: 4 a-blocks of 16 rows each (wave rows q0 + w*64 .. +63)
    const u16* qp = Qkv + (size_t)(q0 + w * 64 + l15) * QKVLD + h * DHEAD + quad * 8;
    bf16x8 qf[4][2];
#pragma unroll
    for (int a = 0; a < 4; ++a) {
        qf[a][0] = *(const bf16x8*)(qp + (size_t)a * 16 * QKVLD);
        qf[a][1] = *(const bf16x8*)(qp + (size_t)a * 16 * QKVLD + 32);
    }

    f32x4 Oa[4][4];
#pragma unroll
    for (int a = 0; a < 4; ++a)
#pragma unroll
        for (int g = 0; g < 4; ++g) Oa[a][g] = (f32x4){0.f, 0.f, 0.f, 0.f};
    float ls[4] = {0.f, 0.f, 0.f, 0.f};

    const int srow = (tid & 127) >> 1;
    const int scol = (tid & 1) * 32;
    const bool isK = (tid < 128);

    // prologue: stage tile 0 into buffer 0
    {
        if (isK) {
            const uint4* kg = (const uint4*)(Qkv + (size_t)(kbase + srow) * QKVLD + 512 + h * DHEAD + scol);
            uint4* kd = (uint4*)&Ks[0][srow * AP + scol];
            kd[0] = kg[0]; kd[1] = kg[1]; kd[2] = kg[2]; kd[3] = kg[3];
        } else {
            const uint4* vg = (const uint4*)(Vtb + ((size_t)h * DHEAD + srow) * N_NODES + kbase + scol);
            uint4* vd = (uint4*)&Vs[0][srow * AP + scol];
            vd[0] = vg[0]; vd[1] = vg[1]; vd[2] = vg[2]; vd[3] = vg[3];
        }
    }
    __syncthreads();

    const int NT = KSPAN / TK;   // 16
    for (int t = 0; t < NT; ++t) {
        const int buf = t & 1;
        const bool more = (t + 1 < NT);
        uint4 s0, s1, s2, s3;
        if (more) {
            // issue next-tile global loads EARLY; latency hides under compute
            const int kn = kbase + (t + 1) * TK;
            if (isK) {
                const uint4* kg = (const uint4*)(Qkv + (size_t)(kn + srow) * QKVLD + 512 + h * DHEAD + scol);
                s0 = kg[0]; s1 = kg[1]; s2 = kg[2]; s3 = kg[3];
            } else {
                const uint4* vg = (const uint4*)(Vtb + ((size_t)h * DHEAD + srow) * N_NODES + kn + scol);
                s0 = vg[0]; s1 = vg[1]; s2 = vg[2]; s3 = vg[3];
            }
        }

        // LDS -> register fragments (reused across all 4 a-blocks)
        bf16x8 kf0[4], kf1[4];
#pragma unroll
        for (int f = 0; f < 4; ++f) {
            const u16* kr = &Ks[buf][(f * 16 + l15) * AP + quad * 8];
            kf0[f] = *(const bf16x8*)kr;
            kf1[f] = *(const bf16x8*)(kr + 32);
        }
        s16x4 vv[4][4];
#pragma unroll
        for (int g = 0; g < 4; ++g)
#pragma unroll
            for (int f = 0; f < 4; ++f)
                vv[f][g] = *(const s16x4*)&Vs[buf][(g * 16 + l15) * AP + f * 16 + quad * 4];

        // ---- rotated pipeline: QK(0) primes; per step a: exppack(a-1) || QK(a); PV(a-1)
        f32x4 StP[4];
#pragma unroll
        for (int f = 0; f < 4; ++f) {
            f32x4 z = (f32x4){0.f, 0.f, 0.f, 0.f};
            z = mfma16(kf0[f], qf[0][0], z);
            StP[f] = mfma16(kf1[f], qf[0][1], z);
        }
#pragma unroll
        for (int a = 1; a <= 4; ++a) {
            // exp/pack of previous a-block (VALU)
            s16x4 pk[4];
#pragma unroll
            for (int f = 0; f < 4; ++f) {
                f32x4 p;
                p[0] = fast_exp2(StP[f][0]);
                p[1] = fast_exp2(StP[f][1]);
                p[2] = fast_exp2(StP[f][2]);
                p[3] = fast_exp2(StP[f][3]);
                ls[a - 1] += (p[0] + p[1]) + (p[2] + p[3]);
                pk[f] = pack_bf4(p);
            }
            // QK of current a-block (MFMA, independent of pk -> overlaps VALU above)
            f32x4 Stn[4];
            if (a < 4) {
#pragma unroll
                for (int f = 0; f < 4; ++f) {
                    f32x4 z = (f32x4){0.f, 0.f, 0.f, 0.f};
                    z = mfma16(kf0[f], qf[a][0], z);
                    Stn[f] = mfma16(kf1[f], qf[a][1], z);
                }
            }
            // PV of previous a-block
#pragma unroll
            for (int f = 0; f < 4; ++f)
#pragma unroll
                for (int g = 0; g < 4; ++g)
                    Oa[a - 1][g] = mfma1k(pk[f], vv[f][g], Oa[a - 1][g]);
            if (a < 4) {
#pragma unroll
                for (int f = 0; f < 4; ++f) StP[f] = Stn[f];
            }
        }

        if (more) {
            // write-late: lands in the other buffer after compute on this one
            if (isK) {
                uint4* kd = (uint4*)&Ks[buf ^ 1][srow * AP + scol];
                kd[0] = s0; kd[1] = s1; kd[2] = s2; kd[3] = s3;
            } else {
                uint4* vd = (uint4*)&Vs[buf ^ 1][srow * AP + scol];
                vd[0] = s0; vd[1] = s1; vd[2] = s2; vd[3] = s3;
            }
            __syncthreads();
        }
    }

#pragma unroll
    for (int a = 0; a < 4; ++a) {
        float s = ls[a];
        s += __shfl_xor(s, 16, 64);
        s += __shfl_xor(s, 32, 64);
        const int rowbase = q0 + w * 64 + a * 16;
        if (quad == 0)
            lpart[(size_t)(rowbase + l15) * 32 + sp * 8 + h] = s;
#pragma unroll
        for (int r = 0; r < 4; ++r) {
            u16* op = Opx + (size_t)(rowbase + quad * 4 + r) * DMODEL + h * DHEAD + l15;
#pragma unroll
            for (int g = 0; g < 4; ++g) op[g * 16] = f2bf(Oa[a][g][r]);
        }
    }
}

// ---------------------------------------------------------------------------
// host side
// ---------------------------------------------------------------------------
static void mgemm64(hipStream_t st, const u16* A, const u16* Bt, const float* bias,
                    const float* res, void* C, int M, int Nn, int K, float scale,
                    int act, int obf16, int ldC, int ldRes) {
    dim3 g(Nn / GBN, M / 64), b(512);
    if (act)
        hipLaunchKernelGGL((mfma_gemm64<1, 1>), g, b, 0, st, A, Bt, bias, res, C, M, Nn, K, scale, ldC, ldRes);
    else if (obf16)
        hipLaunchKernelGGL((mfma_gemm64<0, 1>), g, b, 0, st, A, Bt, bias, res, C, M, Nn, K, scale, ldC, ldRes);
    else
        hipLaunchKernelGGL((mfma_gemm64<0, 0>), g, b, 0, st, A, Bt, bias, res, C, M, Nn, K, scale, ldC, ldRes);
}

extern "C" void kernel_launch(void* const* d_in, const int* in_sizes, int n_in,
                              void* d_out, int out_size, void* d_ws, size_t ws_size,
                              hipStream_t stream) {
    const float* x    = (const float*)d_in[0];
    const int*   ei   = (const int*)d_in[1];
    const float* ew   = (const float*)d_in[2];
    const float* Wg   = (const float*)d_in[3];
    const float* bg   = (const float*)d_in[4];
    const float* ln1s = (const float*)d_in[5];
    const float* ln1b = (const float*)d_in[6];
    const float* Wq   = (const float*)d_in[7];
    const float* bq   = (const float*)d_in[8];
    const float* Wk   = (const float*)d_in[9];
    const float* bk   = (const float*)d_in[10];
    const float* Wv   = (const float*)d_in[11];
    const float* bv   = (const float*)d_in[12];
    const float* Wo   = (const float*)d_in[13];
    const float* bo   = (const float*)d_in[14];
    const float* ln2s = (const float*)d_in[15];
    const float* ln2b = (const float*)d_in[16];
    const float* W1   = (const float*)d_in[17];
    const float* b1   = (const float*)d_in[18];
    const float* W2   = (const float*)d_in[19];
    const float* b2   = (const float*)d_in[20];
    const float* Wa   = (const float*)d_in[21];
    const float* ba   = (const float*)d_in[22];
    float* out = (float*)d_out;
    float* ws  = (float*)d_ws;

    const size_t SLOT = (size_t)N_NODES * DMODEL;  // 2M floats = 8 MB

    u16* xtb = (u16*)ws;
    u16* Ob0 = (u16*)ws;               // splits 0,1 (after gather consumes xtb)
    float* lpart = ws + SLOT;          // [4096][32] fp32 = 512 KB
    int*   esrc  = (int*)(ws + SLOT + 327680);
    float* eww   = (float*)(esrc + NEDGE);
    int*   off   = (int*)(eww + NEDGE);
    int*   cur   = off + 4100;
    int*   cnt   = cur + 4096;
    u16* Ob1 = (u16*)(ws + 2 * SLOT);  // splits 2,3
    u16* hb  = (u16*)(ws + 3 * SLOT);
    u16* h2b = hb + SLOT;
    u16*   qkvb = (u16*)(ws + 4 * SLOT);
    float* x1   = ws + 4 * SLOT;
    u16*   vtb  = (u16*)(ws + 5 * SLOT) + SLOT;
    u16* midb = (u16*)(ws + 6 * SLOT);
    u16* catb = (u16*)(ws + 8 * SLOT);
    u16* xb   = catb;
    u16* Wgt = (u16*)(ws + 9 * SLOT);
    u16* Wqt = Wgt + 262144;
    u16* Wkt = Wqt + 262144;
    u16* Wvt = Wkt + 262144;
    u16* Wot = Wvt + 262144;
    u16* W1t = Wot + 262144;
    u16* W2t = W1t + 1048576;
    u16* Wat = W2t + 1048576;
    float* deg  = (float*)(Wat + 524288);
    float* dinv = deg + N_NODES;

    hipLaunchKernelGGL(prep_kernel, dim3(7952), dim3(256), 0, stream,
                       Wg, Wq, Wk, Wv, Wo, W1, W2, Wa,
                       Wgt, Wqt, Wkt, Wvt, Wot, W1t, W2t, Wat,
                       x, xb, ln1s, ln1b, hb, deg, cnt);

    hipLaunchKernelGGL(qkvg_gemm, dim3(16, 32), dim3(512), 0, stream,
                       xb, hb, Wgt, bq, bk, bv, xtb, qkvb, vtb);

    hipLaunchKernelGGL(gcn_count_kernel, dim3(NEDGE / 256), dim3(256), 0, stream, ei, ew, deg, cnt);
    hipLaunchKernelGGL(gcn_prefix_kernel, dim3(1), dim3(256), 0, stream, cnt, off, cur, deg, dinv);
    hipLaunchKernelGGL(gcn_fill_kernel, dim3(NEDGE / 256), dim3(256), 0, stream, ei, ew, cur, esrc, eww);
    hipLaunchKernelGGL(gcn_gather_kernel, dim3(N_NODES), dim3(256), 0, stream,
                       xtb, off, esrc, eww, dinv, bg, catb);

    hipLaunchKernelGGL(attn_kernel, dim3(NHEAD, N_NODES / TQ, NSPLIT), dim3(256), 0, stream,
                       qkvb, vtb, Ob0, Ob1, lpart);

    hipLaunchKernelGGL(wo_gemm, dim3(4, 64), dim3(512), 0, stream,
                       Ob0, Ob1, lpart, Wot, bo, x, x1);

    hipLaunchKernelGGL(ln_kernel, dim3(N_NODES), dim3(256), 0, stream, x1, ln2s, ln2b, h2b);
    // W1: 128x128-tile high-intensity GEMM (grid 16x32 = 512 blocks)
    hipLaunchKernelGGL((mfma_gemm128<1, 1>), dim3(DFF / 128, N_NODES / 128), dim3(512), 0, stream,
                       h2b, W1t, b1, nullptr, midb, N_NODES, DFF, DMODEL, 1.0f, DFF, DFF);
    mgemm64(stream, midb, W2t, b2, x1, catb + 512, N_NODES, DMODEL, DFF, 1.0f, 0, 1, 1024, DMODEL);

    mgemm64(stream, catb, Wat, ba, x, out, N_NODES, DMODEL, 2 * DMODEL, 1.0f, 0, 0, DMODEL, DMODEL);
}